// Round 3
// baseline (2116.002 us; speedup 1.0000x reference)
//
#include <hip/hip_runtime.h>
#include <hip/hip_bf16.h>
#include <math.h>

// LDCA forward — f32 compute, bf16 for the big MLP intermediate, aliased workspace.
// B=4 C=256 H=W=96 HID=64 G=2 GC=32 KS=3 NK=9 MLP=1024

#define HH 96
#define WWD 96
#define HWP 9216
#define EPSV 1e-5f
#define RFV 9.0f
#define SCALEV 0.125f

typedef __hip_bfloat16 bf16;

__device__ inline float ldf(const float* p) { return *p; }
__device__ inline float ldf(const bf16* p) { return __bfloat162float(*p); }
__device__ inline void stf(float* p, float v) { *p = v; }
__device__ inline void stf(bf16* p, float v) { *p = __float2bfloat16(v); }

// ---------------- LN stats over Cn planar channels (per pixel) ----------------
__global__ __launch_bounds__(256) void k_ln_stats(const float* __restrict__ in,
                                                  float* __restrict__ mout,
                                                  float* __restrict__ rout, int Cn) {
  int idx = blockIdx.x * 256 + threadIdx.x;  // over B*HW
  int b = idx / HWP, p = idx % HWP;
  const float* base = in + (size_t)b * Cn * HWP + p;
  float s = 0.f, ss = 0.f;
  for (int c = 0; c < Cn; ++c) { float v = base[(size_t)c * HWP]; s += v; ss += v * v; }
  float m = s / (float)Cn;
  float var = ss / (float)Cn - m * m;
  mout[idx] = m;
  rout[idx] = rsqrtf(var + EPSV);
}

// ---------------- fold LN gamma/beta into weight matrix ----------------
__global__ __launch_bounds__(256) void k_prep_w(const float* __restrict__ w,
                                                const float* __restrict__ g,
                                                const float* __restrict__ bb,
                                                float* __restrict__ wg, float* __restrict__ sg,
                                                float* __restrict__ wb, int O, int K) {
  int o = blockIdx.x * 256 + threadIdx.x;
  if (o >= O) return;
  float sgv = 0.f, wbv = 0.f;
  for (int c = 0; c < K; ++c) {
    float wv = w[(size_t)o * K + c];
    float t = wv * g[c];
    wg[(size_t)o * K + c] = t;
    sgv += t;
    wbv += wv * bb[c];
  }
  sg[o] = sgv; wb[o] = wbv;
}

// ---------------- generic planar GEMM ----------------
// out[b,o,p] = epilogue(sum_c W[o,c]*in[b,c,p]); 256 px x 32 outs per block.
template <typename TI, typename TO>
__global__ __launch_bounds__(256) void k_gemm(const TI* __restrict__ in,
                                              const float* __restrict__ W,
                                              const float* __restrict__ ms,
                                              const float* __restrict__ rs,
                                              const float* __restrict__ sg,
                                              const float* __restrict__ wb,
                                              const float* __restrict__ bias,
                                              const float* __restrict__ resid,
                                              TO* __restrict__ out, int K, int O) {
  __shared__ float wl[32][64];
  int tp = threadIdx.x & 63, to = threadIdx.x >> 6;
  int p0 = blockIdx.x * 256;
  int o0 = blockIdx.y * 32;
  int b = blockIdx.z;
  float acc[8][4];
#pragma unroll
  for (int j = 0; j < 8; ++j)
#pragma unroll
    for (int k = 0; k < 4; ++k) acc[j][k] = 0.f;

  for (int kb = 0; kb < K; kb += 64) {
    __syncthreads();
#pragma unroll
    for (int i = 0; i < 8; ++i) {
      int idx = threadIdx.x + i * 256;
      int oo = idx >> 6, cc2 = idx & 63;
      wl[oo][cc2] = W[(size_t)(o0 + oo) * K + kb + cc2];
    }
    __syncthreads();
    const TI* inb = in + (size_t)(b * K + kb) * HWP + p0;
    for (int c = 0; c < 64; ++c) {
      const TI* ip = inb + (size_t)c * HWP;
      float x0 = ldf(ip + tp), x1 = ldf(ip + tp + 64);
      float x2 = ldf(ip + tp + 128), x3 = ldf(ip + tp + 192);
#pragma unroll
      for (int j = 0; j < 8; ++j) {
        float wv = wl[to * 8 + j][c];
        acc[j][0] += wv * x0; acc[j][1] += wv * x1;
        acc[j][2] += wv * x2; acc[j][3] += wv * x3;
      }
    }
  }
#pragma unroll
  for (int j = 0; j < 8; ++j) {
    int o = o0 + to * 8 + j;
    float sgv = sg ? sg[o] : 0.f;
    float add = (wb ? wb[o] : 0.f) + (bias ? bias[o] : 0.f);
#pragma unroll
    for (int k2 = 0; k2 < 4; ++k2) {
      int p = p0 + tp + k2 * 64;
      float v = acc[j][k2];
      if (rs) { int bp = b * HWP + p; float r = rs[bp]; v = r * v - r * ms[bp] * sgv; }
      v += add;
      if (resid) v += resid[(size_t)(b * O + o) * HWP + p];
      stf(out + (size_t)(b * O + o) * HWP + p, v);
    }
  }
}

// ---------------- repack qkv1/kv2c into channel-contiguous kvT / qT ----------------
__global__ __launch_bounds__(256) void k_repack(const float* __restrict__ qkv1,
                                                const float* __restrict__ kv2c,
                                                float* __restrict__ kvT,
                                                float* __restrict__ qT) {
  __shared__ float tile[64][65];
  int tp = threadIdx.x & 63, tq = threadIdx.x >> 6;
  int p0 = blockIdx.x * 64;
  int bg = blockIdx.y;
  int z = blockIdx.z;
  if (z == 2 && bg >= 4) return;
  int b = (z == 2) ? bg : (bg >> 1);
  int g = bg & 1;
#pragma unroll 4
  for (int i = 0; i < 16; ++i) {
    int ch = tq * 16 + i;
    const float* src;
    if (z == 0) {
      int sc = 64 + (ch >> 5) * 64 + g * 32 + (ch & 31);
      src = qkv1 + (size_t)(b * 192 + sc) * HWP;
    } else if (z == 1) {
      int sc = (ch >> 5) * 64 + g * 32 + (ch & 31);
      src = kv2c + (size_t)(b * 128 + sc) * HWP;
    } else {
      src = qkv1 + (size_t)(b * 192 + ch) * HWP;
    }
    tile[ch][tp] = src[p0 + tp];
  }
  __syncthreads();
  float scale = (z == 2) ? SCALEV : 1.f;
  float* dst;
  if (z == 0)      dst = kvT + ((size_t)bg * HWP) * 64;
  else if (z == 1) dst = kvT + ((size_t)(8 + bg) * HWP) * 64;
  else             dst = qT + ((size_t)b * HWP) * 64;
#pragma unroll 4
  for (int i = 0; i < 16; ++i) {
    int pp = tq * 16 + i;
    dst[(size_t)(p0 + pp) * 64 + tp] = tile[tp][pp] * scale;
  }
}

// ---------------- offset branch: depthwise 3x3 on q1 ----------------
__global__ __launch_bounds__(256) void k_dw3x3(const float* __restrict__ qkv1,
                                               const float* __restrict__ dww,
                                               float* __restrict__ t) {
  int p = blockIdx.x * 256 + threadIdx.x;
  int c = blockIdx.y, bg = blockIdx.z;
  int b = bg >> 1, g = bg & 1;
  int y = p / WWD, x = p % WWD;
  const float* src = qkv1 + (size_t)(b * 192 + g * 32 + c) * HWP;
  float acc = 0.f;
#pragma unroll
  for (int ky = 0; ky < 3; ++ky) {
    int yy = y + ky - 1;
    if (yy < 0 || yy >= HH) continue;
#pragma unroll
    for (int kx = 0; kx < 3; ++kx) {
      int xx = x + kx - 1;
      if (xx < 0 || xx >= WWD) continue;
      acc += src[yy * WWD + xx] * dww[c * 9 + ky * 3 + kx];
    }
  }
  t[(size_t)(bg * 32 + c) * HWP + p] = acc;
}

// ---------------- offset branch: LN(32ch) + exact GELU, in place ----------------
__global__ __launch_bounds__(256) void k_ln_gelu32(float* __restrict__ t,
                                                   const float* __restrict__ g,
                                                   const float* __restrict__ bb) {
  int idx = blockIdx.x * 256 + threadIdx.x;  // over 8*HW
  int bg = idx / HWP, p = idx % HWP;
  float* base = t + (size_t)bg * 32 * HWP + p;
  float s = 0.f, ss = 0.f;
#pragma unroll
  for (int c = 0; c < 32; ++c) { float v = base[(size_t)c * HWP]; s += v; ss += v * v; }
  float m = s / 32.f;
  float var = ss / 32.f - m * m;
  float r = rsqrtf(var + EPSV);
#pragma unroll
  for (int c = 0; c < 32; ++c) {
    float v = base[(size_t)c * HWP];
    float xn = (v - m) * r * g[c] + bb[c];
    base[(size_t)c * HWP] = 0.5f * xn * (1.f + erff(xn * 0.70710678118654752f));
  }
}

// ---------------- offset branch: 3x3 conv 32->18, tanh*RF + base ----------------
__global__ __launch_bounds__(64) void k_conv18(const float* __restrict__ t,
                                               const float* __restrict__ w,
                                               const float* __restrict__ bias,
                                               float* __restrict__ offo, int s) {
  __shared__ float wl[288];
  int oc = blockIdx.y, bg = blockIdx.z;
  for (int i = threadIdx.x; i < 288; i += 64) wl[i] = w[oc * 288 + i];
  __syncthreads();
  int p = blockIdx.x * 64 + threadIdx.x;
  int y = p / WWD, x = p % WWD;
  const float* tb = t + (size_t)bg * 32 * HWP;
  float acc = bias[oc];
  for (int c = 0; c < 32; ++c) {
    const float* tc = tb + (size_t)c * HWP;
#pragma unroll
    for (int ky = 0; ky < 3; ++ky) {
      int yy = y + ky - 1;
      if (yy < 0 || yy >= HH) continue;
#pragma unroll
      for (int kx = 0; kx < 3; ++kx) {
        int xx = x + kx - 1;
        if (xx < 0 || xx >= WWD) continue;
        acc += tc[yy * WWD + xx] * wl[c * 9 + ky * 3 + kx];
      }
    }
  }
  int n = oc >> 1, d = oc & 1;
  float basev = d ? (float)(n % 3 - 1) : (float)(n / 3 - 1);
  offo[((size_t)(s * 8 + bg) * 18 + oc) * HWP + p] = tanhf(acc) * RFV + basev;
}

// ---------------- fused deformable sampling + softmax + PV ----------------
__global__ __launch_bounds__(256) void k_attn(const float* __restrict__ qT,
                                              const float* __restrict__ kvT,
                                              const float* __restrict__ offo,
                                              const float* __restrict__ rpb,
                                              float* __restrict__ o_att) {
  __shared__ float rl[576];
  for (int i = threadIdx.x; i < 576; i += 256) rl[i] = rpb[i];
  __syncthreads();
  int pix = blockIdx.x * 4 + (threadIdx.x >> 6);
  int l = threadIdx.x & 63;
  int b = pix / HWP, p = pix % HWP;
  int y = p / WWD, x = p % WWD;
  int g = l >> 5, c = l & 31;
  int bg = b * 2 + g;
  float qv = qT[(size_t)(b * HWP + p) * 64 + l];
  float scores[18], vv[18];
#pragma unroll
  for (int s = 0; s < 2; ++s) {
    const float* offp = offo + ((size_t)(s * 8 + bg) * 18) * HWP + p;
    const float* kvb = kvT + ((size_t)(s * 8 + bg) * HWP) * 64;
#pragma unroll
    for (int n = 0; n < 9; ++n) {
      float ry = (float)y + offp[(size_t)(2 * n) * HWP];
      float rx = (float)x + offp[(size_t)(2 * n + 1) * HWP];
      float y0f = floorf(ry), x0f = floorf(rx);
      float wy = ry - y0f, wx = rx - x0f;
      int y0 = (int)y0f, x0 = (int)x0f;
      float ka = 0.f, va = 0.f;
#pragma unroll
      for (int cy = 0; cy < 2; ++cy) {
        int yi = y0 + cy;
        if (yi < 0 || yi >= HH) continue;
        float wyc = cy ? wy : 1.f - wy;
#pragma unroll
        for (int cx = 0; cx < 2; ++cx) {
          int xi = x0 + cx;
          if (xi < 0 || xi >= WWD) continue;
          float wgt = wyc * (cx ? wx : 1.f - wx);
          const float* row = kvb + (size_t)(yi * WWD + xi) * 64;
          ka += wgt * row[c];
          va += wgt * row[32 + c];
        }
      }
      float sp = qv * (ka + rl[n * 64 + l]);
      sp += __shfl_xor(sp, 1);
      sp += __shfl_xor(sp, 2);
      sp += __shfl_xor(sp, 4);
      sp += __shfl_xor(sp, 8);
      sp += __shfl_xor(sp, 16);
      sp += __shfl_xor(sp, 32);
      scores[s * 9 + n] = sp;
      vv[s * 9 + n] = va;
    }
  }
  float mx = scores[0];
#pragma unroll
  for (int i = 1; i < 18; ++i) mx = fmaxf(mx, scores[i]);
  float sum = 0.f;
#pragma unroll
  for (int i = 0; i < 18; ++i) { scores[i] = expf(scores[i] - mx); sum += scores[i]; }
  float inv = 1.f / sum;
  float o = 0.f;
#pragma unroll
  for (int i = 0; i < 18; ++i) o += scores[i] * vv[i];
  o_att[(size_t)(b * HWP + p) * 64 + l] = o * inv;
}

// ---------------- transpose o_att [b][p][64] -> [b][64][p] ----------------
__global__ __launch_bounds__(256) void k_transp64(const float* __restrict__ src,
                                                  float* __restrict__ dst) {
  __shared__ float tile[64][65];
  int tp = threadIdx.x & 63, tq = threadIdx.x >> 6;
  int p0 = blockIdx.x * 64;
  int b = blockIdx.y;
#pragma unroll 4
  for (int i = 0; i < 16; ++i) {
    int pp = tq * 16 + i;
    tile[pp][tp] = src[(size_t)(b * HWP + p0 + pp) * 64 + tp];
  }
  __syncthreads();
#pragma unroll 4
  for (int i = 0; i < 16; ++i) {
    int ch = tq * 16 + i;
    dst[(size_t)(b * 64 + ch) * HWP + p0 + tp] = tile[tp][ch];
  }
}

// ---------------- depthwise 3x3 + gelu(h + hd), IN PLACE on bf16 planes ----------------
__global__ __launch_bounds__(256) void k_dwgelu(bf16* __restrict__ h,
                                                const float* __restrict__ w,
                                                const float* __restrict__ bias) {
  __shared__ float pl[HWP];  // 36 KB: full 96x96 plane
  int j = blockIdx.x, b = blockIdx.y;
  const size_t base = ((size_t)b * 1024 + j) * HWP;
  for (int i = threadIdx.x; i < HWP; i += 256) pl[i] = __bfloat162float(h[base + i]);
  __syncthreads();
  float wl[9];
#pragma unroll
  for (int k = 0; k < 9; ++k) wl[k] = w[j * 9 + k];
  float bv = bias[j];
  for (int i = threadIdx.x; i < HWP; i += 256) {
    int y = i / WWD, x = i % WWD;
    float acc = bv;
#pragma unroll
    for (int ky = 0; ky < 3; ++ky) {
      int yy = y + ky - 1;
      if (yy < 0 || yy >= HH) continue;
#pragma unroll
      for (int kx = 0; kx < 3; ++kx) {
        int xx = x + kx - 1;
        if (xx < 0 || xx >= WWD) continue;
        acc += pl[yy * WWD + xx] * wl[ky * 3 + kx];
      }
    }
    float v = pl[i] + acc;
    h[base + i] = __float2bfloat16(0.5f * v * (1.f + erff(v * 0.70710678118654752f)));
  }
}

extern "C" void kernel_launch(void* const* d_in, const int* in_sizes, int n_in,
                              void* d_out, int out_size, void* d_ws, size_t ws_size,
                              hipStream_t stream) {
  const float* x      = (const float*)d_in[0];
  const float* y      = (const float*)d_in[1];
  const float* g11    = (const float*)d_in[2];
  const float* b11    = (const float*)d_in[3];
  const float* g21    = (const float*)d_in[4];
  const float* b21    = (const float*)d_in[5];
  const float* g12    = (const float*)d_in[6];
  const float* b12    = (const float*)d_in[7];
  const float* w_qkv1 = (const float*)d_in[8];
  const float* w_qkv2 = (const float*)d_in[9];
  const float* o1dw   = (const float*)d_in[10];
  const float* o1lg   = (const float*)d_in[11];
  const float* o1lb   = (const float*)d_in[12];
  const float* o1w    = (const float*)d_in[13];
  const float* o1bi   = (const float*)d_in[14];
  const float* o2dw   = (const float*)d_in[15];
  const float* o2lg   = (const float*)d_in[16];
  const float* o2lb   = (const float*)d_in[17];
  const float* o2w    = (const float*)d_in[18];
  const float* o2bi   = (const float*)d_in[19];
  const float* rpb    = (const float*)d_in[20];
  const float* proj_w = (const float*)d_in[21];
  const float* proj_b = (const float*)d_in[22];
  const float* fc1_w  = (const float*)d_in[23];
  const float* fc1_b  = (const float*)d_in[24];
  const float* dw_w   = (const float*)d_in[25];
  const float* dw_b   = (const float*)d_in[26];
  const float* fc2_w  = (const float*)d_in[27];
  const float* fc2_b  = (const float*)d_in[28];
  float* out = (float*)d_out;

  // ---- aliased workspace layout (floats). Region A is reused across stages.
  // Stage1: qkv1 kv2c tbuf o_attT kvT qT offb o_att (33,325,056 floats).
  // Stage2: o1 overlays [0, 9437184) (qkv1+kv2c head, dead);
  //         hbuf(bf16) overlays f-offset [9437184, 28311552) (all dead by fc1).
  // Total ws use: 33,892,992 floats = 135.6 MB.
  float* ws = (float*)d_ws;
  float* qkv1   = ws;                 // 7,077,888
  float* kv2c   = ws + 7077888;       // 4,718,592
  float* tbuf   = ws + 11796480;      // 2,359,296
  float* o_attT = ws + 14155776;      // 2,359,296
  float* kvT    = ws + 16515072;      // 9,437,184
  float* qT     = ws + 25952256;      // 2,359,296
  float* offb   = ws + 28311552;      // 2,654,208
  float* o_att  = ws + 30965760;      // 2,359,296
  float* o1     = ws;                 // 9,437,184 (stage 2, overlays qkv1/kv2c)
  bf16*  hbuf   = (bf16*)(ws + 9437184);  // 37,748,736 bf16 (stage 2)
  float* stats  = ws + 33325056;      // 221,184
  float* m_x = stats, *r_x = stats + 36864, *m_y = stats + 73728, *r_y = stats + 110592;
  float* m_o = stats + 147456, *r_o = stats + 184320;
  float* Wg1 = ws + 33546240;         // 49,152
  float* sg1 = Wg1 + 49152, *wb1 = sg1 + 192;
  float* Wg2 = ws + 33595776;         // 32,768
  float* sg2 = Wg2 + 32768, *wb2 = sg2 + 128;
  float* Wgf = ws + 33628800;         // 262,144
  float* sgf = Wgf + 262144, *wbf = sgf + 1024;
  // end: ws + 33,892,992

  // 1. fold LN into projection weights
  k_prep_w<<<1, 256, 0, stream>>>(w_qkv1, g11, b11, Wg1, sg1, wb1, 192, 256);
  k_prep_w<<<1, 256, 0, stream>>>(w_qkv2, g21, b21, Wg2, sg2, wb2, 128, 256);
  k_prep_w<<<4, 256, 0, stream>>>(fc1_w, g12, b12, Wgf, sgf, wbf, 1024, 256);

  // 2. per-pixel LN stats for x, y
  k_ln_stats<<<144, 256, 0, stream>>>(x, m_x, r_x, 256);
  k_ln_stats<<<144, 256, 0, stream>>>(y, m_y, r_y, 256);

  // 3. qkv projections (LN folded)
  k_gemm<float, float><<<dim3(36, 6, 4), 256, 0, stream>>>(x, Wg1, m_x, r_x, sg1, wb1,
                                                           nullptr, nullptr, qkv1, 256, 192);
  k_gemm<float, float><<<dim3(36, 4, 4), 256, 0, stream>>>(y, Wg2, m_y, r_y, sg2, wb2,
                                                           nullptr, nullptr, kv2c, 256, 128);

  // 4. repack to channel-contiguous kvT + qT
  k_repack<<<dim3(144, 8, 3), 256, 0, stream>>>(qkv1, kv2c, kvT, qT);

  // 5. offset branches (sequential, share tbuf)
  k_dw3x3<<<dim3(36, 32, 8), 256, 0, stream>>>(qkv1, o1dw, tbuf);
  k_ln_gelu32<<<288, 256, 0, stream>>>(tbuf, o1lg, o1lb);
  k_conv18<<<dim3(144, 18, 8), 64, 0, stream>>>(tbuf, o1w, o1bi, offb, 0);
  k_dw3x3<<<dim3(36, 32, 8), 256, 0, stream>>>(qkv1, o2dw, tbuf);
  k_ln_gelu32<<<288, 256, 0, stream>>>(tbuf, o2lg, o2lb);
  k_conv18<<<dim3(144, 18, 8), 64, 0, stream>>>(tbuf, o2w, o2bi, offb, 1);

  // 6. fused deformable sampling + attention
  k_attn<<<9216, 256, 0, stream>>>(qT, kvT, offb, rpb, o_att);

  // 7. proj + residual(x)  (o1 overlays qkv1/kv2c — both dead now)
  k_transp64<<<dim3(144, 4), 256, 0, stream>>>(o_att, o_attT);
  k_gemm<float, float><<<dim3(36, 8, 4), 256, 0, stream>>>(o_attT, proj_w, nullptr, nullptr,
                                                           nullptr, nullptr, proj_b, x, o1, 64, 256);

  // 8. MLP: LN stats, fc1 (LN folded, bf16 out), in-place dw+gelu, fc2 + residual
  k_ln_stats<<<144, 256, 0, stream>>>(o1, m_o, r_o, 256);
  k_gemm<float, bf16><<<dim3(36, 32, 4), 256, 0, stream>>>(o1, Wgf, m_o, r_o, sgf, wbf,
                                                           fc1_b, nullptr, hbuf, 256, 1024);
  k_dwgelu<<<dim3(1024, 4), 256, 0, stream>>>(hbuf, dw_w, dw_b);
  k_gemm<bf16, float><<<dim3(36, 8, 4), 256, 0, stream>>>(hbuf, fc2_w, nullptr, nullptr,
                                                          nullptr, nullptr, fc2_b, o1, out, 1024, 256);
}

// Round 4
// 1975.684 us; speedup vs baseline: 1.0710x; 1.0710x over previous
//
#include <hip/hip_runtime.h>
#include <math.h>

// LDCA forward — bf16 MFMA GEMMs on channel-contiguous activations.
// B=4 C=256 H=W=96 HID=64 G=2 GC=32 KS=3 NK=9 MLP=1024

#define HH 96
#define WWD 96
#define HWP 9216
#define EPSV 1e-5f
#define RFV 9.0f

typedef unsigned short ushort;
typedef __attribute__((ext_vector_type(8))) short short8v;
typedef __attribute__((ext_vector_type(8))) ushort ushort8v;
typedef __attribute__((ext_vector_type(4))) float f32x4;

__device__ inline ushort f2bf(float f) {
  union { float f; unsigned u; } v; v.f = f;
  unsigned r = v.u + 0x7FFFu + ((v.u >> 16) & 1u);
  return (ushort)(r >> 16);
}
__device__ inline float bf2f(ushort h) {
  union { unsigned u; float f; } v; v.u = ((unsigned)h) << 16;
  return v.f;
}

__device__ inline void stf(float* p, float v) { *p = v; }
__device__ inline void stf(ushort* p, float v) { *p = f2bf(v); }

// stage 16 elements (f32->bf16 convert, or bf16 copy) into LDS
__device__ inline void stage16(const float* __restrict__ s, ushort* d) {
  const float4* s4 = (const float4*)s;
  float4 v0 = s4[0], v1 = s4[1], v2 = s4[2], v3 = s4[3];
  ushort8v r0, r1;
  r0[0] = f2bf(v0.x); r0[1] = f2bf(v0.y); r0[2] = f2bf(v0.z); r0[3] = f2bf(v0.w);
  r0[4] = f2bf(v1.x); r0[5] = f2bf(v1.y); r0[6] = f2bf(v1.z); r0[7] = f2bf(v1.w);
  r1[0] = f2bf(v2.x); r1[1] = f2bf(v2.y); r1[2] = f2bf(v2.z); r1[3] = f2bf(v2.w);
  r1[4] = f2bf(v3.x); r1[5] = f2bf(v3.y); r1[6] = f2bf(v3.z); r1[7] = f2bf(v3.w);
  ((ushort8v*)d)[0] = r0; ((ushort8v*)d)[1] = r1;
}
__device__ inline void stage16(const ushort* __restrict__ s, ushort* d) {
  ((ushort8v*)d)[0] = ((const ushort8v*)s)[0];
  ((ushort8v*)d)[1] = ((const ushort8v*)s)[1];
}

// ---------------- LN stats over Cn planar channels (per pixel) ----------------
__global__ __launch_bounds__(256) void k_ln_stats(const float* __restrict__ in,
                                                  float* __restrict__ mout,
                                                  float* __restrict__ rout, int Cn) {
  int idx = blockIdx.x * 256 + threadIdx.x;
  int b = idx / HWP, p = idx % HWP;
  const float* base = in + (size_t)b * Cn * HWP + p;
  float s = 0.f, ss = 0.f;
  for (int c = 0; c < Cn; ++c) { float v = base[(size_t)c * HWP]; s += v; ss += v * v; }
  float m = s / (float)Cn;
  float var = ss / (float)Cn - m * m;
  mout[idx] = m;
  rout[idx] = rsqrtf(var + EPSV);
}

// ---------------- LN stats, channel-contiguous input (256 ch) ----------------
__global__ __launch_bounds__(256) void k_ln_stats_cc(const float* __restrict__ in,
                                                     float* __restrict__ mout,
                                                     float* __restrict__ rout) {
  int px = blockIdx.x * 4 + (threadIdx.x >> 6);
  int lane = threadIdx.x & 63;
  float4 v = *(const float4*)(in + (size_t)px * 256 + lane * 4);
  float s = v.x + v.y + v.z + v.w;
  float ss = v.x * v.x + v.y * v.y + v.z * v.z + v.w * v.w;
#pragma unroll
  for (int d = 1; d < 64; d <<= 1) { s += __shfl_xor(s, d); ss += __shfl_xor(ss, d); }
  if (lane == 0) {
    float m = s / 256.f;
    mout[px] = m;
    rout[px] = rsqrtf(ss / 256.f - m * m + EPSV);
  }
}

// ---------------- prep: bf16 weights + LN-fold vectors ----------------
// wbf[o,c] = bf16(w*g*sc); sg[o] = sum(bf16-rounded); wb[o] = sc*sum(w*beta)
__global__ __launch_bounds__(256) void k_prepbf(const float* __restrict__ w,
                                                const float* __restrict__ g,
                                                const float* __restrict__ beta,
                                                ushort* __restrict__ wbf,
                                                float* __restrict__ sg, float* __restrict__ wb,
                                                int O, int K, int scaleRows) {
  int o = blockIdx.x * 256 + threadIdx.x;
  if (o >= O) return;
  float sc = (o < scaleRows) ? 0.125f : 1.f;
  float sgv = 0.f, wbv = 0.f;
  for (int c = 0; c < K; ++c) {
    float wv = w[(size_t)o * K + c];
    float t = wv * (g ? g[c] : 1.f) * sc;
    ushort u = f2bf(t);
    wbf[(size_t)o * K + c] = u;
    sgv += bf2f(u);
    wbv += wv * (beta ? beta[c] : 0.f);
  }
  if (sg) sg[o] = sgv;
  if (wb) wb[o] = wbv * sc;
}

// ---------------- planar f32 -> channel-contiguous bf16 ----------------
__global__ __launch_bounds__(256) void k_tocc(const float* __restrict__ src,
                                              ushort* __restrict__ dst) {
  __shared__ float tile[64][65];
  int tp = threadIdx.x & 63, tq = threadIdx.x >> 6;
  int p0 = blockIdx.x * 64, c0 = blockIdx.y * 64, b = blockIdx.z;
#pragma unroll 4
  for (int i = 0; i < 16; ++i) {
    int ch = tq * 16 + i;
    tile[ch][tp] = src[((size_t)b * 256 + c0 + ch) * HWP + p0 + tp];
  }
  __syncthreads();
#pragma unroll 4
  for (int i = 0; i < 16; ++i) {
    int pp = tq * 16 + i;
    dst[((size_t)b * HWP + p0 + pp) * 256 + c0 + tp] = f2bf(tile[tp][pp]);
  }
}

// ---------------- MFMA GEMM (orientation B): out_cc[b][p][o] ----------------
// out = epi( sum_k act[b][p][k] * Wbf[o][k] ), tile 128p x 64o, 4 waves 2x2.
template <typename TI, typename TO, bool LNF, bool RES>
__global__ __launch_bounds__(256) void k_gemmB(const TI* __restrict__ act,
                                               const ushort* __restrict__ Wbf,
                                               const float* __restrict__ ms,
                                               const float* __restrict__ rs,
                                               const float* __restrict__ sg,
                                               const float* __restrict__ wb,
                                               const float* __restrict__ bias,
                                               const ushort* __restrict__ resid,
                                               TO* __restrict__ outp, int K, int O) {
  __shared__ ushort at[128][56];  // padded: 112 B row stride (16B-aligned)
  __shared__ ushort wt[64][56];
  int tid = threadIdx.x;
  int lane = tid & 63, wv = tid >> 6;
  int wr = wv >> 1, wc = wv & 1;
  int p0 = blockIdx.x * 128, o0 = blockIdx.y * 64, b = blockIdx.z;
  size_t pb = (size_t)b * HWP;
  int l15 = lane & 15, lk = (lane >> 4) * 8;
  f32x4 acc[4][2];
#pragma unroll
  for (int rt = 0; rt < 4; ++rt)
#pragma unroll
    for (int ct = 0; ct < 2; ++ct) { acc[rt][ct][0] = 0.f; acc[rt][ct][1] = 0.f; acc[rt][ct][2] = 0.f; acc[rt][ct][3] = 0.f; }

  for (int kb = 0; kb < K; kb += 32) {
    __syncthreads();
    {
      int p = tid >> 1, kh = (tid & 1) * 16;
      stage16(act + (pb + p0 + p) * (size_t)K + kb + kh, &at[p][kh]);
    }
    if (tid < 128) {
      int o = tid >> 1, kh = (tid & 1) * 16;
      stage16(Wbf + (size_t)(o0 + o) * K + kb + kh, &wt[o][kh]);
    }
    __syncthreads();
    short8v a[4], bb[2];
#pragma unroll
    for (int rt = 0; rt < 4; ++rt) a[rt] = *(const short8v*)&at[wr * 64 + rt * 16 + l15][lk];
#pragma unroll
    for (int ct = 0; ct < 2; ++ct) bb[ct] = *(const short8v*)&wt[wc * 32 + ct * 16 + l15][lk];
#pragma unroll
    for (int rt = 0; rt < 4; ++rt)
#pragma unroll
      for (int ct = 0; ct < 2; ++ct)
        acc[rt][ct] = __builtin_amdgcn_mfma_f32_16x16x32_bf16(a[rt], bb[ct], acc[rt][ct], 0, 0, 0);
  }
  // epilogue: D col(lane&15)=o, row((lane>>4)*4+j)=p  [m89-verified mapping]
#pragma unroll
  for (int rt = 0; rt < 4; ++rt) {
    int pbase = p0 + wr * 64 + rt * 16 + (lane >> 4) * 4;
#pragma unroll
    for (int j = 0; j < 4; ++j) {
      int p = pbase + j;
      float rr = 0.f, mm = 0.f;
      if (LNF) { rr = rs[b * HWP + p]; mm = ms[b * HWP + p]; }
#pragma unroll
      for (int ct = 0; ct < 2; ++ct) {
        int o = o0 + wc * 32 + ct * 16 + l15;
        float v = acc[rt][ct][j];
        if (LNF) v = rr * v - rr * mm * sg[o];
        if (wb) v += wb[o];
        if (bias) v += bias[o];
        if (RES) v += bf2f(resid[(pb + p) * (size_t)O + o]);
        stf(&outp[(pb + p) * (size_t)O + o], v);
      }
    }
  }
}

// ---------------- q1 slice of qkv1cc -> planar f32 (x8 to unscale) ----------------
__global__ __launch_bounds__(256) void k_q1p(const float* __restrict__ qkv1cc,
                                             float* __restrict__ q1p) {
  __shared__ float tile[64][65];
  int tp = threadIdx.x & 63, tq = threadIdx.x >> 6;
  int p0 = blockIdx.x * 64, b = blockIdx.y;
#pragma unroll 4
  for (int i = 0; i < 16; ++i) {
    int pp = tq * 16 + i;
    tile[tp][pp] = qkv1cc[((size_t)b * HWP + p0 + pp) * 192 + tp];
  }
  __syncthreads();
#pragma unroll 4
  for (int i = 0; i < 16; ++i) {
    int ch = tq * 16 + i;
    q1p[((size_t)b * 64 + ch) * HWP + p0 + tp] = tile[ch][tp] * 8.f;
  }
}

// ---------------- offset branch: depthwise 3x3 on q1 (planar) ----------------
__global__ __launch_bounds__(256) void k_dw3x3(const float* __restrict__ q1p,
                                               const float* __restrict__ dww,
                                               float* __restrict__ t) {
  int p = blockIdx.x * 256 + threadIdx.x;
  int c = blockIdx.y, bg = blockIdx.z;
  int b = bg >> 1, g = bg & 1;
  int y = p / WWD, x = p % WWD;
  const float* src = q1p + ((size_t)b * 64 + g * 32 + c) * HWP;
  float acc = 0.f;
#pragma unroll
  for (int ky = 0; ky < 3; ++ky) {
    int yy = y + ky - 1;
    if (yy < 0 || yy >= HH) continue;
#pragma unroll
    for (int kx = 0; kx < 3; ++kx) {
      int xx = x + kx - 1;
      if (xx < 0 || xx >= WWD) continue;
      acc += src[yy * WWD + xx] * dww[c * 9 + ky * 3 + kx];
    }
  }
  t[(size_t)(bg * 32 + c) * HWP + p] = acc;
}

// ---------------- offset branch: LN(32ch) + exact GELU, in place ----------------
__global__ __launch_bounds__(256) void k_ln_gelu32(float* __restrict__ t,
                                                   const float* __restrict__ g,
                                                   const float* __restrict__ bb) {
  int idx = blockIdx.x * 256 + threadIdx.x;
  int bg = idx / HWP, p = idx % HWP;
  float* base = t + (size_t)bg * 32 * HWP + p;
  float s = 0.f, ss = 0.f;
#pragma unroll
  for (int c = 0; c < 32; ++c) { float v = base[(size_t)c * HWP]; s += v; ss += v * v; }
  float m = s / 32.f;
  float var = ss / 32.f - m * m;
  float r = rsqrtf(var + EPSV);
#pragma unroll
  for (int c = 0; c < 32; ++c) {
    float v = base[(size_t)c * HWP];
    float xn = (v - m) * r * g[c] + bb[c];
    base[(size_t)c * HWP] = 0.5f * xn * (1.f + erff(xn * 0.70710678118654752f));
  }
}

// ---------------- offset branch: 3x3 conv 32->18, tanh*RF + base ----------------
__global__ __launch_bounds__(64) void k_conv18(const float* __restrict__ t,
                                               const float* __restrict__ w,
                                               const float* __restrict__ bias,
                                               float* __restrict__ offo, int s) {
  __shared__ float wl[288];
  int oc = blockIdx.y, bg = blockIdx.z;
  for (int i = threadIdx.x; i < 288; i += 64) wl[i] = w[oc * 288 + i];
  __syncthreads();
  int p = blockIdx.x * 64 + threadIdx.x;
  int y = p / WWD, x = p % WWD;
  const float* tb = t + (size_t)bg * 32 * HWP;
  float acc = bias[oc];
  for (int c = 0; c < 32; ++c) {
    const float* tc = tb + (size_t)c * HWP;
#pragma unroll
    for (int ky = 0; ky < 3; ++ky) {
      int yy = y + ky - 1;
      if (yy < 0 || yy >= HH) continue;
#pragma unroll
      for (int kx = 0; kx < 3; ++kx) {
        int xx = x + kx - 1;
        if (xx < 0 || xx >= WWD) continue;
        acc += tc[yy * WWD + xx] * wl[c * 9 + ky * 3 + kx];
      }
    }
  }
  int n = oc >> 1, d = oc & 1;
  float basev = d ? (float)(n % 3 - 1) : (float)(n / 3 - 1);
  offo[((size_t)(s * 8 + bg) * 18 + oc) * HWP + p] = tanhf(acc) * RFV + basev;
}

// ---------------- fused deformable sampling + softmax + PV ----------------
// q/k/v read channel-contiguous: qkv1cc [b][p][192] (q scaled), kv2cc [b][p][128]
__global__ __launch_bounds__(256) void k_attn(const float* __restrict__ qkv1cc,
                                              const float* __restrict__ kv2cc,
                                              const float* __restrict__ offo,
                                              const float* __restrict__ rpb,
                                              float* __restrict__ o_att) {
  __shared__ float rl[576];
  for (int i = threadIdx.x; i < 576; i += 256) rl[i] = rpb[i];
  __syncthreads();
  int pix = blockIdx.x * 4 + (threadIdx.x >> 6);
  int l = threadIdx.x & 63;
  int b = pix / HWP, p = pix % HWP;
  int y = p / WWD, x = p % WWD;
  int g = l >> 5;
  int bg = b * 2 + g;
  float qv = qkv1cc[((size_t)b * HWP + p) * 192 + l];
  float scores[18], vvv[18];
#pragma unroll
  for (int s = 0; s < 2; ++s) {
    const float* offp = offo + ((size_t)(s * 8 + bg) * 18) * HWP + p;
    const float* kvb = s ? (kv2cc + (size_t)b * HWP * 128) : (qkv1cc + (size_t)b * HWP * 192);
    int stride = s ? 128 : 192;
    int koff = s ? 0 : 64;
#pragma unroll
    for (int n = 0; n < 9; ++n) {
      float ry = (float)y + offp[(size_t)(2 * n) * HWP];
      float rx = (float)x + offp[(size_t)(2 * n + 1) * HWP];
      float y0f = floorf(ry), x0f = floorf(rx);
      float wy = ry - y0f, wx = rx - x0f;
      int y0 = (int)y0f, x0 = (int)x0f;
      float ka = 0.f, va = 0.f;
#pragma unroll
      for (int cy = 0; cy < 2; ++cy) {
        int yi = y0 + cy;
        if (yi < 0 || yi >= HH) continue;
        float wyc = cy ? wy : 1.f - wy;
#pragma unroll
        for (int cx = 0; cx < 2; ++cx) {
          int xi = x0 + cx;
          if (xi < 0 || xi >= WWD) continue;
          float wgt = wyc * (cx ? wx : 1.f - wx);
          const float* row = kvb + (size_t)(yi * WWD + xi) * stride + koff;
          ka += wgt * row[l];
          va += wgt * row[64 + l];
        }
      }
      float sp = qv * (ka + rl[n * 64 + l]);
      sp += __shfl_xor(sp, 1);
      sp += __shfl_xor(sp, 2);
      sp += __shfl_xor(sp, 4);
      sp += __shfl_xor(sp, 8);
      sp += __shfl_xor(sp, 16);
      sp += __shfl_xor(sp, 32);
      scores[s * 9 + n] = sp;
      vvv[s * 9 + n] = va;
    }
  }
  float mx = scores[0];
#pragma unroll
  for (int i = 1; i < 18; ++i) mx = fmaxf(mx, scores[i]);
  float sum = 0.f;
#pragma unroll
  for (int i = 0; i < 18; ++i) { scores[i] = expf(scores[i] - mx); sum += scores[i]; }
  float inv = 1.f / sum;
  float o = 0.f;
#pragma unroll
  for (int i = 0; i < 18; ++i) o += scores[i] * vvv[i];
  o_att[((size_t)b * HWP + p) * 64 + l] = o * inv;
}

// ---------------- depthwise 3x3 + gelu(h+hd), channel-contiguous bf16 ----------------
__global__ __launch_bounds__(256) void k_dwgelu_cc(const ushort* __restrict__ h,
                                                   const float* __restrict__ w,
                                                   const float* __restrict__ bias,
                                                   ushort* __restrict__ h2) {
  __shared__ ushort tileh[324][48];  // 18x18 px halo tile x 32 ch (96 B rows, aligned)
  __shared__ float wl[32][9];
  __shared__ float bl[32];
  int tid = threadIdx.x;
  int tile = blockIdx.x, chb = blockIdx.y, b = blockIdx.z;
  int ty0 = (tile / 6) * 16, tx0 = (tile % 6) * 16;
  size_t base = ((size_t)b * HWP) * 1024 + chb * 32;
  for (int i = tid; i < 288; i += 256) wl[i / 9][i % 9] = w[(chb * 32 + i / 9) * 9 + i % 9];
  if (tid < 32) bl[tid] = bias[chb * 32 + tid];
  for (int idx = tid; idx < 324; idx += 256) {
    int py = idx / 18, px = idx % 18;
    int gy = ty0 - 1 + py, gx = tx0 - 1 + px;
    ushort8v* d = (ushort8v*)&tileh[idx][0];
    if (gy >= 0 && gy < HH && gx >= 0 && gx < WWD) {
      const ushort8v* sv = (const ushort8v*)(h + base + (size_t)(gy * WWD + gx) * 1024);
      d[0] = sv[0]; d[1] = sv[1]; d[2] = sv[2]; d[3] = sv[3];
    } else {
      ushort8v z; 
#pragma unroll
      for (int e = 0; e < 8; ++e) z[e] = 0;
      d[0] = z; d[1] = z; d[2] = z; d[3] = z;
    }
  }
  __syncthreads();
  int ly = tid >> 4, lx = tid & 15;
  float a[32];
#pragma unroll
  for (int c = 0; c < 32; ++c) a[c] = bl[c];
#pragma unroll
  for (int dy = 0; dy < 3; ++dy)
#pragma unroll
    for (int dx = 0; dx < 3; ++dx) {
      const ushort8v* t = (const ushort8v*)&tileh[(ly + dy) * 18 + lx + dx][0];
      int tap = dy * 3 + dx;
#pragma unroll
      for (int cq = 0; cq < 4; ++cq) {
        ushort8v vv = t[cq];
#pragma unroll
        for (int e = 0; e < 8; ++e) a[cq * 8 + e] += bf2f(vv[e]) * wl[cq * 8 + e][tap];
      }
    }
  const ushort8v* ctr = (const ushort8v*)&tileh[(ly + 1) * 18 + lx + 1][0];
  ushort8v* outv = (ushort8v*)(h2 + base + (size_t)((ty0 + ly) * WWD + tx0 + lx) * 1024);
#pragma unroll
  for (int cq = 0; cq < 4; ++cq) {
    ushort8v vv = ctr[cq];
    ushort8v rv;
#pragma unroll
    for (int e = 0; e < 8; ++e) {
      float v = bf2f(vv[e]) + a[cq * 8 + e];
      rv[e] = f2bf(0.5f * v * (1.f + erff(v * 0.70710678118654752f)));
    }
    outv[cq] = rv;
  }
}

// ---------------- final: out_planar = fc2cc + o1cc (transpose-add) ----------------
__global__ __launch_bounds__(256) void k_fromcc(const float* __restrict__ fc2cc,
                                                const float* __restrict__ o1cc,
                                                float* __restrict__ outp) {
  __shared__ float tile[64][65];
  int tp = threadIdx.x & 63, tq = threadIdx.x >> 6;
  int p0 = blockIdx.x * 64, c0 = blockIdx.y * 64, b = blockIdx.z;
#pragma unroll 4
  for (int i = 0; i < 16; ++i) {
    int pp = tq * 16 + i;
    size_t idx = ((size_t)b * HWP + p0 + pp) * 256 + c0 + tp;
    tile[tp][pp] = fc2cc[idx] + o1cc[idx];
  }
  __syncthreads();
#pragma unroll 4
  for (int i = 0; i < 16; ++i) {
    int ch = tq * 16 + i;
    outp[((size_t)b * 256 + c0 + ch) * HWP + p0 + tp] = tile[ch][tp];
  }
}

extern "C" void kernel_launch(void* const* d_in, const int* in_sizes, int n_in,
                              void* d_out, int out_size, void* d_ws, size_t ws_size,
                              hipStream_t stream) {
  const float* x      = (const float*)d_in[0];
  const float* y      = (const float*)d_in[1];
  const float* g11    = (const float*)d_in[2];
  const float* b11    = (const float*)d_in[3];
  const float* g21    = (const float*)d_in[4];
  const float* b21    = (const float*)d_in[5];
  const float* g12    = (const float*)d_in[6];
  const float* b12    = (const float*)d_in[7];
  const float* w_qkv1 = (const float*)d_in[8];
  const float* w_qkv2 = (const float*)d_in[9];
  const float* o1dw   = (const float*)d_in[10];
  const float* o1lg   = (const float*)d_in[11];
  const float* o1lb   = (const float*)d_in[12];
  const float* o1w    = (const float*)d_in[13];
  const float* o1bi   = (const float*)d_in[14];
  const float* o2dw   = (const float*)d_in[15];
  const float* o2lg   = (const float*)d_in[16];
  const float* o2lb   = (const float*)d_in[17];
  const float* o2w    = (const float*)d_in[18];
  const float* o2bi   = (const float*)d_in[19];
  const float* rpb    = (const float*)d_in[20];
  const float* proj_w = (const float*)d_in[21];
  const float* proj_b = (const float*)d_in[22];
  const float* fc1_w  = (const float*)d_in[23];
  const float* fc1_b  = (const float*)d_in[24];
  const float* dw_w   = (const float*)d_in[25];
  const float* dw_b   = (const float*)d_in[26];
  const float* fc2_w  = (const float*)d_in[27];
  const float* fc2_b  = (const float*)d_in[28];
  float* out = (float*)d_out;

  // ---- workspace layout (word offsets; aliased by live range) ----
  // Stage1 [0, 26247168): xcc ycc(->q1p,tbuf) qkv1cc kv2cc offb o_att — dead after proj.
  // Stage2: hcc [0,18874368)w, h2cc [18874368,37748736)w, o1cc [37748736,47185920)w,
  //         fc2cc [0,9437184)w (after hcc dead). Total ~191 MB.
  float* ws = (float*)d_ws;
  ushort* xcc   = (ushort*)(ws + 0);           // 9,437,184 bf16
  ushort* ycc   = (ushort*)(ws + 4718592);     // 9,437,184 bf16
  float*  q1p   = ws + 4718592;                // 2,359,296 f32 (after ycc dead)
  float*  tbuf  = ws + 7077888;                // 2,359,296 f32
  float*  qkv1cc= ws + 9437184;                // 7,077,888 f32
  float*  kv2cc = ws + 16515072;               // 4,718,592 f32
  float*  offb  = ws + 21233664;               // 2,654,208 f32
  float*  o_att = ws + 23887872;               // 2,359,296 f32
  ushort* hcc   = (ushort*)(ws + 0);           // 37,748,736 bf16 (stage 2)
  ushort* h2cc  = (ushort*)(ws + 18874368);    // 37,748,736 bf16
  float*  o1cc  = ws + 37748736;               // 9,437,184 f32
  float*  fc2cc = ws + 0;                      // 9,437,184 f32 (after hcc dead)
  const size_t SW = 47185920;
  float* m_x = ws + SW, *r_x = m_x + 36864, *m_y = r_x + 36864, *r_y = m_y + 36864;
  float* m_o = r_y + 36864, *r_o = m_o + 36864;
  ushort* Wg1bf = (ushort*)(ws + SW + 221184);      // 49,152 bf16
  float* sg1 = ws + SW + 245760, *wb1 = sg1 + 192;
  ushort* Wg2bf = (ushort*)(ws + SW + 246144);      // 32,768 bf16
  float* sg2 = ws + SW + 262528, *wb2 = sg2 + 128;
  ushort* Wgfbf = (ushort*)(ws + SW + 262784);      // 262,144 bf16
  float* sgf = ws + SW + 393856, *wbf = sgf + 1024;
  ushort* projbf = (ushort*)(ws + SW + 395904);     // 16,384 bf16
  ushort* fc2bf  = (ushort*)(ws + SW + 404096);     // 262,144 bf16

  // 1. weights -> bf16 (+LN fold); SCALE=0.125 folded into q rows of qkv1
  k_prepbf<<<1, 256, 0, stream>>>(w_qkv1, g11, b11, Wg1bf, sg1, wb1, 192, 256, 64);
  k_prepbf<<<1, 256, 0, stream>>>(w_qkv2, g21, b21, Wg2bf, sg2, wb2, 128, 256, 0);
  k_prepbf<<<4, 256, 0, stream>>>(fc1_w, g12, b12, Wgfbf, sgf, wbf, 1024, 256, 0);
  k_prepbf<<<1, 256, 0, stream>>>(proj_w, nullptr, nullptr, projbf, nullptr, nullptr, 256, 64, 0);
  k_prepbf<<<1, 256, 0, stream>>>(fc2_w, nullptr, nullptr, fc2bf, nullptr, nullptr, 256, 1024, 0);

  // 2. LN stats + cc-bf16 activations
  k_ln_stats<<<144, 256, 0, stream>>>(x, m_x, r_x, 256);
  k_ln_stats<<<144, 256, 0, stream>>>(y, m_y, r_y, 256);
  k_tocc<<<dim3(144, 4, 4), 256, 0, stream>>>(x, xcc);
  k_tocc<<<dim3(144, 4, 4), 256, 0, stream>>>(y, ycc);

  // 3. qkv projections (MFMA, LN folded)
  k_gemmB<ushort, float, true, false><<<dim3(72, 3, 4), 256, 0, stream>>>(
      xcc, Wg1bf, m_x, r_x, sg1, wb1, nullptr, nullptr, qkv1cc, 256, 192);
  k_gemmB<ushort, float, true, false><<<dim3(72, 2, 4), 256, 0, stream>>>(
      ycc, Wg2bf, m_y, r_y, sg2, wb2, nullptr, nullptr, kv2cc, 256, 128);

  // 4. offset branches (q1 planar via x8-unscale transpose)
  k_q1p<<<dim3(144, 4), 256, 0, stream>>>(qkv1cc, q1p);
  k_dw3x3<<<dim3(36, 32, 8), 256, 0, stream>>>(q1p, o1dw, tbuf);
  k_ln_gelu32<<<288, 256, 0, stream>>>(tbuf, o1lg, o1lb);
  k_conv18<<<dim3(144, 18, 8), 64, 0, stream>>>(tbuf, o1w, o1bi, offb, 0);
  k_dw3x3<<<dim3(36, 32, 8), 256, 0, stream>>>(q1p, o2dw, tbuf);
  k_ln_gelu32<<<288, 256, 0, stream>>>(tbuf, o2lg, o2lb);
  k_conv18<<<dim3(144, 18, 8), 64, 0, stream>>>(tbuf, o2w, o2bi, offb, 1);

  // 5. fused deformable sampling + attention
  k_attn<<<9216, 256, 0, stream>>>(qkv1cc, kv2cc, offb, rpb, o_att);

  // 6. proj (MFMA) + residual(xcc)
  k_gemmB<float, float, false, true><<<dim3(72, 4, 4), 256, 0, stream>>>(
      o_att, projbf, nullptr, nullptr, nullptr, nullptr, proj_b, xcc, o1cc, 64, 256);

  // 7. MLP: LN stats, fc1 (MFMA, LN folded, bf16 out), dw+gelu cc, fc2 (MFMA)
  k_ln_stats_cc<<<9216, 256, 0, stream>>>(o1cc, m_o, r_o);
  k_gemmB<float, ushort, true, false><<<dim3(72, 16, 4), 256, 0, stream>>>(
      o1cc, Wgfbf, m_o, r_o, sgf, wbf, fc1_b, nullptr, hcc, 256, 1024);
  k_dwgelu_cc<<<dim3(36, 32, 4), 256, 0, stream>>>(hcc, dw_w, dw_b, h2cc);
  k_gemmB<ushort, float, false, false><<<dim3(72, 4, 4), 256, 0, stream>>>(
      h2cc, fc2bf, nullptr, nullptr, nullptr, nullptr, fc2_b, nullptr, fc2cc, 1024, 256);

  // 8. final transpose + residual(o1cc)
  k_fromcc<<<dim3(144, 4, 4), 256, 0, stream>>>(fc2cc, o1cc, out);
}

// Round 5
// 1383.908 us; speedup vs baseline: 1.5290x; 1.4276x over previous
//
#include <hip/hip_runtime.h>
#include <math.h>

// LDCA forward — bf16 MFMA GEMMs on channel-contiguous activations.
// B=4 C=256 H=W=96 HID=64 G=2 GC=32 KS=3 NK=9 MLP=1024

#define HH 96
#define WWD 96
#define HWP 9216
#define EPSV 1e-5f
#define RFV 9.0f

typedef unsigned short ushort;
typedef __attribute__((ext_vector_type(8))) short short8v;
typedef __attribute__((ext_vector_type(8))) ushort ushort8v;
typedef __attribute__((ext_vector_type(4))) float f32x4;

__device__ inline ushort f2bf(float f) {
  union { float f; unsigned u; } v; v.f = f;
  unsigned r = v.u + 0x7FFFu + ((v.u >> 16) & 1u);
  return (ushort)(r >> 16);
}
__device__ inline float bf2f(ushort h) {
  union { unsigned u; float f; } v; v.u = ((unsigned)h) << 16;
  return v.f;
}

__device__ inline void stf(float* p, float v) { *p = v; }
__device__ inline void stf(ushort* p, float v) { *p = f2bf(v); }

// stage 16 elements (f32->bf16 convert, or bf16 copy) into LDS
__device__ inline void stage16(const float* __restrict__ s, ushort* d) {
  const float4* s4 = (const float4*)s;
  float4 v0 = s4[0], v1 = s4[1], v2 = s4[2], v3 = s4[3];
  ushort8v r0, r1;
  r0[0] = f2bf(v0.x); r0[1] = f2bf(v0.y); r0[2] = f2bf(v0.z); r0[3] = f2bf(v0.w);
  r0[4] = f2bf(v1.x); r0[5] = f2bf(v1.y); r0[6] = f2bf(v1.z); r0[7] = f2bf(v1.w);
  r1[0] = f2bf(v2.x); r1[1] = f2bf(v2.y); r1[2] = f2bf(v2.z); r1[3] = f2bf(v2.w);
  r1[4] = f2bf(v3.x); r1[5] = f2bf(v3.y); r1[6] = f2bf(v3.z); r1[7] = f2bf(v3.w);
  ((ushort8v*)d)[0] = r0; ((ushort8v*)d)[1] = r1;
}
__device__ inline void stage16(const ushort* __restrict__ s, ushort* d) {
  ((ushort8v*)d)[0] = ((const ushort8v*)s)[0];
  ((ushort8v*)d)[1] = ((const ushort8v*)s)[1];
}

// ---------------- LN stats over Cn planar channels (per pixel) ----------------
__global__ __launch_bounds__(256) void k_ln_stats(const float* __restrict__ in,
                                                  float* __restrict__ mout,
                                                  float* __restrict__ rout, int Cn) {
  int idx = blockIdx.x * 256 + threadIdx.x;
  int b = idx / HWP, p = idx % HWP;
  const float* base = in + (size_t)b * Cn * HWP + p;
  float s = 0.f, ss = 0.f;
  for (int c = 0; c < Cn; ++c) { float v = base[(size_t)c * HWP]; s += v; ss += v * v; }
  float m = s / (float)Cn;
  float var = ss / (float)Cn - m * m;
  mout[idx] = m;
  rout[idx] = rsqrtf(var + EPSV);
}

// ---------------- LN stats, channel-contiguous input (256 ch) ----------------
__global__ __launch_bounds__(256) void k_ln_stats_cc(const float* __restrict__ in,
                                                     float* __restrict__ mout,
                                                     float* __restrict__ rout) {
  int px = blockIdx.x * 4 + (threadIdx.x >> 6);
  int lane = threadIdx.x & 63;
  float4 v = *(const float4*)(in + (size_t)px * 256 + lane * 4);
  float s = v.x + v.y + v.z + v.w;
  float ss = v.x * v.x + v.y * v.y + v.z * v.z + v.w * v.w;
#pragma unroll
  for (int d = 1; d < 64; d <<= 1) { s += __shfl_xor(s, d); ss += __shfl_xor(ss, d); }
  if (lane == 0) {
    float m = s / 256.f;
    mout[px] = m;
    rout[px] = rsqrtf(ss / 256.f - m * m + EPSV);
  }
}

// ---------------- prep: bf16 weights + LN-fold vectors (1 wave / row) ----------------
// wbf[o,c] = bf16(w*g*sc); sg[o] = sum(bf16-rounded); wb[o] = sc*sum(w*beta)
__global__ __launch_bounds__(256) void k_prepbf(const float* __restrict__ w,
                                                const float* __restrict__ g,
                                                const float* __restrict__ beta,
                                                ushort* __restrict__ wbf,
                                                float* __restrict__ sg, float* __restrict__ wb,
                                                int O, int K, int scaleRows) {
  int o = blockIdx.x * 4 + (threadIdx.x >> 6);
  int lane = threadIdx.x & 63;
  if (o >= O) return;
  float sc = (o < scaleRows) ? 0.125f : 1.f;
  float sgv = 0.f, wbv = 0.f;
  for (int c = lane; c < K; c += 64) {
    float wv = w[(size_t)o * K + c];
    float t = wv * (g ? g[c] : 1.f) * sc;
    ushort u = f2bf(t);
    wbf[(size_t)o * K + c] = u;
    sgv += bf2f(u);
    wbv += wv * (beta ? beta[c] : 0.f);
  }
#pragma unroll
  for (int d = 1; d < 64; d <<= 1) { sgv += __shfl_xor(sgv, d); wbv += __shfl_xor(wbv, d); }
  if (lane == 0) {
    if (sg) sg[o] = sgv;
    if (wb) wb[o] = wbv * sc;
  }
}

// ---------------- planar f32 -> channel-contiguous bf16 ----------------
__global__ __launch_bounds__(256) void k_tocc(const float* __restrict__ src,
                                              ushort* __restrict__ dst) {
  __shared__ float tile[64][65];
  int tp = threadIdx.x & 63, tq = threadIdx.x >> 6;
  int p0 = blockIdx.x * 64, c0 = blockIdx.y * 64, b = blockIdx.z;
#pragma unroll 4
  for (int i = 0; i < 16; ++i) {
    int ch = tq * 16 + i;
    tile[ch][tp] = src[((size_t)b * 256 + c0 + ch) * HWP + p0 + tp];
  }
  __syncthreads();
#pragma unroll 4
  for (int i = 0; i < 16; ++i) {
    int pp = tq * 16 + i;
    dst[((size_t)b * HWP + p0 + pp) * 256 + c0 + tp] = f2bf(tile[tp][pp]);
  }
}

// ---------------- MFMA GEMM (orientation B): out_cc[b][p][o] ----------------
// out = epi( sum_k act[b][p][k] * Wbf[o][k] ), tile 128p x 64o, 4 waves 2x2.
template <typename TI, typename TO, bool LNF, bool RES>
__global__ __launch_bounds__(256) void k_gemmB(const TI* __restrict__ act,
                                               const ushort* __restrict__ Wbf,
                                               const float* __restrict__ ms,
                                               const float* __restrict__ rs,
                                               const float* __restrict__ sg,
                                               const float* __restrict__ wb,
                                               const float* __restrict__ bias,
                                               const ushort* __restrict__ resid,
                                               TO* __restrict__ outp, int K, int O) {
  __shared__ ushort at[128][56];  // padded: 112 B row stride (16B-aligned)
  __shared__ ushort wt[64][56];
  int tid = threadIdx.x;
  int lane = tid & 63, wv = tid >> 6;
  int wr = wv >> 1, wc = wv & 1;
  int p0 = blockIdx.x * 128, o0 = blockIdx.y * 64, b = blockIdx.z;
  size_t pb = (size_t)b * HWP;
  int l15 = lane & 15, lk = (lane >> 4) * 8;
  f32x4 acc[4][2];
#pragma unroll
  for (int rt = 0; rt < 4; ++rt)
#pragma unroll
    for (int ct = 0; ct < 2; ++ct) { acc[rt][ct][0] = 0.f; acc[rt][ct][1] = 0.f; acc[rt][ct][2] = 0.f; acc[rt][ct][3] = 0.f; }

  for (int kb = 0; kb < K; kb += 32) {
    __syncthreads();
    {
      int p = tid >> 1, kh = (tid & 1) * 16;
      stage16(act + (pb + p0 + p) * (size_t)K + kb + kh, &at[p][kh]);
    }
    if (tid < 128) {
      int o = tid >> 1, kh = (tid & 1) * 16;
      stage16(Wbf + (size_t)(o0 + o) * K + kb + kh, &wt[o][kh]);
    }
    __syncthreads();
    short8v a[4], bb[2];
#pragma unroll
    for (int rt = 0; rt < 4; ++rt) a[rt] = *(const short8v*)&at[wr * 64 + rt * 16 + l15][lk];
#pragma unroll
    for (int ct = 0; ct < 2; ++ct) bb[ct] = *(const short8v*)&wt[wc * 32 + ct * 16 + l15][lk];
#pragma unroll
    for (int rt = 0; rt < 4; ++rt)
#pragma unroll
      for (int ct = 0; ct < 2; ++ct)
        acc[rt][ct] = __builtin_amdgcn_mfma_f32_16x16x32_bf16(a[rt], bb[ct], acc[rt][ct], 0, 0, 0);
  }
  // epilogue: D col(lane&15)=o, row((lane>>4)*4+j)=p  [m89-verified mapping]
#pragma unroll
  for (int rt = 0; rt < 4; ++rt) {
    int pbase = p0 + wr * 64 + rt * 16 + (lane >> 4) * 4;
#pragma unroll
    for (int j = 0; j < 4; ++j) {
      int p = pbase + j;
      float rr = 0.f, mm = 0.f;
      if (LNF) { rr = rs[b * HWP + p]; mm = ms[b * HWP + p]; }
#pragma unroll
      for (int ct = 0; ct < 2; ++ct) {
        int o = o0 + wc * 32 + ct * 16 + l15;
        float v = acc[rt][ct][j];
        if (LNF) v = rr * v - rr * mm * sg[o];
        if (wb) v += wb[o];
        if (bias) v += bias[o];
        if (RES) v += bf2f(resid[(pb + p) * (size_t)O + o]);
        stf(&outp[(pb + p) * (size_t)O + o], v);
      }
    }
  }
}

// ---------------- q1 slice of qkv1cc -> planar f32 (x8 to unscale) ----------------
__global__ __launch_bounds__(256) void k_q1p(const float* __restrict__ qkv1cc,
                                             float* __restrict__ q1p) {
  __shared__ float tile[64][65];
  int tp = threadIdx.x & 63, tq = threadIdx.x >> 6;
  int p0 = blockIdx.x * 64, b = blockIdx.y;
#pragma unroll 4
  for (int i = 0; i < 16; ++i) {
    int pp = tq * 16 + i;
    tile[tp][pp] = qkv1cc[((size_t)b * HWP + p0 + pp) * 192 + tp];
  }
  __syncthreads();
#pragma unroll 4
  for (int i = 0; i < 16; ++i) {
    int ch = tq * 16 + i;
    q1p[((size_t)b * 64 + ch) * HWP + p0 + tp] = tile[ch][tp] * 8.f;
  }
}

// ---------------- offset branch: depthwise 3x3 on q1 (planar) ----------------
__global__ __launch_bounds__(256) void k_dw3x3(const float* __restrict__ q1p,
                                               const float* __restrict__ dww,
                                               float* __restrict__ t) {
  int p = blockIdx.x * 256 + threadIdx.x;
  int c = blockIdx.y, bg = blockIdx.z;
  int b = bg >> 1, g = bg & 1;
  int y = p / WWD, x = p % WWD;
  const float* src = q1p + ((size_t)b * 64 + g * 32 + c) * HWP;
  float acc = 0.f;
#pragma unroll
  for (int ky = 0; ky < 3; ++ky) {
    int yy = y + ky - 1;
    if (yy < 0 || yy >= HH) continue;
#pragma unroll
    for (int kx = 0; kx < 3; ++kx) {
      int xx = x + kx - 1;
      if (xx < 0 || xx >= WWD) continue;
      acc += src[yy * WWD + xx] * dww[c * 9 + ky * 3 + kx];
    }
  }
  t[(size_t)(bg * 32 + c) * HWP + p] = acc;
}

// ---------------- offset branch: LN(32ch) + exact GELU, in place ----------------
__global__ __launch_bounds__(256) void k_ln_gelu32(float* __restrict__ t,
                                                   const float* __restrict__ g,
                                                   const float* __restrict__ bb) {
  int idx = blockIdx.x * 256 + threadIdx.x;
  int bg = idx / HWP, p = idx % HWP;
  float* base = t + (size_t)bg * 32 * HWP + p;
  float s = 0.f, ss = 0.f;
#pragma unroll
  for (int c = 0; c < 32; ++c) { float v = base[(size_t)c * HWP]; s += v; ss += v * v; }
  float m = s / 32.f;
  float var = ss / 32.f - m * m;
  float r = rsqrtf(var + EPSV);
#pragma unroll
  for (int c = 0; c < 32; ++c) {
    float v = base[(size_t)c * HWP];
    float xn = (v - m) * r * g[c] + bb[c];
    base[(size_t)c * HWP] = 0.5f * xn * (1.f + erff(xn * 0.70710678118654752f));
  }
}

// ---------------- offset branch: 3x3 conv 32->18, tanh*RF + base ----------------
__global__ __launch_bounds__(64) void k_conv18(const float* __restrict__ t,
                                               const float* __restrict__ w,
                                               const float* __restrict__ bias,
                                               float* __restrict__ offo, int s) {
  __shared__ float wl[288];
  int oc = blockIdx.y, bg = blockIdx.z;
  for (int i = threadIdx.x; i < 288; i += 64) wl[i] = w[oc * 288 + i];
  __syncthreads();
  int p = blockIdx.x * 64 + threadIdx.x;
  int y = p / WWD, x = p % WWD;
  const float* tb = t + (size_t)bg * 32 * HWP;
  float acc = bias[oc];
  for (int c = 0; c < 32; ++c) {
    const float* tc = tb + (size_t)c * HWP;
#pragma unroll
    for (int ky = 0; ky < 3; ++ky) {
      int yy = y + ky - 1;
      if (yy < 0 || yy >= HH) continue;
#pragma unroll
      for (int kx = 0; kx < 3; ++kx) {
        int xx = x + kx - 1;
        if (xx < 0 || xx >= WWD) continue;
        acc += tc[yy * WWD + xx] * wl[c * 9 + ky * 3 + kx];
      }
    }
  }
  int n = oc >> 1, d = oc & 1;
  float basev = d ? (float)(n % 3 - 1) : (float)(n / 3 - 1);
  offo[((size_t)(s * 8 + bg) * 18 + oc) * HWP + p] = tanhf(acc) * RFV + basev;
}

// ---------------- fused deformable sampling + softmax + PV ----------------
// q/k/v read channel-contiguous: qkv1cc [b][p][192] (q scaled), kv2cc [b][p][128]
__global__ __launch_bounds__(256) void k_attn(const float* __restrict__ qkv1cc,
                                              const float* __restrict__ kv2cc,
                                              const float* __restrict__ offo,
                                              const float* __restrict__ rpb,
                                              float* __restrict__ o_att) {
  __shared__ float rl[576];
  for (int i = threadIdx.x; i < 576; i += 256) rl[i] = rpb[i];
  __syncthreads();
  int pix = blockIdx.x * 4 + (threadIdx.x >> 6);
  int l = threadIdx.x & 63;
  int b = pix / HWP, p = pix % HWP;
  int y = p / WWD, x = p % WWD;
  int g = l >> 5;
  int bg = b * 2 + g;
  float qv = qkv1cc[((size_t)b * HWP + p) * 192 + l];
  float scores[18], vvv[18];
#pragma unroll
  for (int s = 0; s < 2; ++s) {
    const float* offp = offo + ((size_t)(s * 8 + bg) * 18) * HWP + p;
    const float* kvb = s ? (kv2cc + (size_t)b * HWP * 128) : (qkv1cc + (size_t)b * HWP * 192);
    int stride = s ? 128 : 192;
    int koff = s ? 0 : 64;
#pragma unroll
    for (int n = 0; n < 9; ++n) {
      float ry = (float)y + offp[(size_t)(2 * n) * HWP];
      float rx = (float)x + offp[(size_t)(2 * n + 1) * HWP];
      float y0f = floorf(ry), x0f = floorf(rx);
      float wy = ry - y0f, wx = rx - x0f;
      int y0 = (int)y0f, x0 = (int)x0f;
      float ka = 0.f, va = 0.f;
#pragma unroll
      for (int cy = 0; cy < 2; ++cy) {
        int yi = y0 + cy;
        if (yi < 0 || yi >= HH) continue;
        float wyc = cy ? wy : 1.f - wy;
#pragma unroll
        for (int cx = 0; cx < 2; ++cx) {
          int xi = x0 + cx;
          if (xi < 0 || xi >= WWD) continue;
          float wgt = wyc * (cx ? wx : 1.f - wx);
          const float* row = kvb + (size_t)(yi * WWD + xi) * stride + koff;
          ka += wgt * row[l];
          va += wgt * row[64 + l];
        }
      }
      float sp = qv * (ka + rl[n * 64 + l]);
      sp += __shfl_xor(sp, 1);
      sp += __shfl_xor(sp, 2);
      sp += __shfl_xor(sp, 4);
      sp += __shfl_xor(sp, 8);
      sp += __shfl_xor(sp, 16);
      sp += __shfl_xor(sp, 32);
      scores[s * 9 + n] = sp;
      vvv[s * 9 + n] = va;
    }
  }
  float mx = scores[0];
#pragma unroll
  for (int i = 1; i < 18; ++i) mx = fmaxf(mx, scores[i]);
  float sum = 0.f;
#pragma unroll
  for (int i = 0; i < 18; ++i) { scores[i] = expf(scores[i] - mx); sum += scores[i]; }
  float inv = 1.f / sum;
  float o = 0.f;
#pragma unroll
  for (int i = 0; i < 18; ++i) o += scores[i] * vvv[i];
  o_att[((size_t)b * HWP + p) * 64 + l] = o * inv;
}

// ---------------- depthwise 3x3 + gelu(h+hd), channel-contiguous bf16 ----------------
__global__ __launch_bounds__(256) void k_dwgelu_cc(const ushort* __restrict__ h,
                                                   const float* __restrict__ w,
                                                   const float* __restrict__ bias,
                                                   ushort* __restrict__ h2) {
  __shared__ ushort tileh[324][48];  // 18x18 px halo tile x 32 ch (96 B rows, aligned)
  __shared__ float wl[32][9];
  __shared__ float bl[32];
  int tid = threadIdx.x;
  int tile = blockIdx.x, chb = blockIdx.y, b = blockIdx.z;
  int ty0 = (tile / 6) * 16, tx0 = (tile % 6) * 16;
  size_t base = ((size_t)b * HWP) * 1024 + chb * 32;
  for (int i = tid; i < 288; i += 256) wl[i / 9][i % 9] = w[(chb * 32 + i / 9) * 9 + i % 9];
  if (tid < 32) bl[tid] = bias[chb * 32 + tid];
  for (int idx = tid; idx < 324; idx += 256) {
    int py = idx / 18, px = idx % 18;
    int gy = ty0 - 1 + py, gx = tx0 - 1 + px;
    ushort8v* d = (ushort8v*)&tileh[idx][0];
    if (gy >= 0 && gy < HH && gx >= 0 && gx < WWD) {
      const ushort8v* sv = (const ushort8v*)(h + base + (size_t)(gy * WWD + gx) * 1024);
      d[0] = sv[0]; d[1] = sv[1]; d[2] = sv[2]; d[3] = sv[3];
    } else {
      ushort8v z;
#pragma unroll
      for (int e = 0; e < 8; ++e) z[e] = 0;
      d[0] = z; d[1] = z; d[2] = z; d[3] = z;
    }
  }
  __syncthreads();
  int ly = tid >> 4, lx = tid & 15;
  float a[32];
#pragma unroll
  for (int c = 0; c < 32; ++c) a[c] = bl[c];
#pragma unroll
  for (int dy = 0; dy < 3; ++dy)
#pragma unroll
    for (int dx = 0; dx < 3; ++dx) {
      const ushort8v* t = (const ushort8v*)&tileh[(ly + dy) * 18 + lx + dx][0];
      int tap = dy * 3 + dx;
#pragma unroll
      for (int cq = 0; cq < 4; ++cq) {
        ushort8v vv = t[cq];
#pragma unroll
        for (int e = 0; e < 8; ++e) a[cq * 8 + e] += bf2f(vv[e]) * wl[cq * 8 + e][tap];
      }
    }
  const ushort8v* ctr = (const ushort8v*)&tileh[(ly + 1) * 18 + lx + 1][0];
  ushort8v* outv = (ushort8v*)(h2 + base + (size_t)((ty0 + ly) * WWD + tx0 + lx) * 1024);
#pragma unroll
  for (int cq = 0; cq < 4; ++cq) {
    ushort8v vv = ctr[cq];
    ushort8v rv;
#pragma unroll
    for (int e = 0; e < 8; ++e) {
      float v = bf2f(vv[e]) + a[cq * 8 + e];
      rv[e] = f2bf(0.5f * v * (1.f + erff(v * 0.70710678118654752f)));
    }
    outv[cq] = rv;
  }
}

// ---------------- final: out_planar = fc2cc + o1cc (transpose-add) ----------------
__global__ __launch_bounds__(256) void k_fromcc(const float* __restrict__ fc2cc,
                                                const float* __restrict__ o1cc,
                                                float* __restrict__ outp) {
  __shared__ float tile[64][65];
  int tp = threadIdx.x & 63, tq = threadIdx.x >> 6;
  int p0 = blockIdx.x * 64, c0 = blockIdx.y * 64, b = blockIdx.z;
#pragma unroll 4
  for (int i = 0; i < 16; ++i) {
    int pp = tq * 16 + i;
    size_t idx = ((size_t)b * HWP + p0 + pp) * 256 + c0 + tp;
    tile[tp][pp] = fc2cc[idx] + o1cc[idx];
  }
  __syncthreads();
#pragma unroll 4
  for (int i = 0; i < 16; ++i) {
    int ch = tq * 16 + i;
    outp[((size_t)b * 256 + c0 + ch) * HWP + p0 + tp] = tile[ch][tp];
  }
}

extern "C" void kernel_launch(void* const* d_in, const int* in_sizes, int n_in,
                              void* d_out, int out_size, void* d_ws, size_t ws_size,
                              hipStream_t stream) {
  const float* x      = (const float*)d_in[0];
  const float* y      = (const float*)d_in[1];
  const float* g11    = (const float*)d_in[2];
  const float* b11    = (const float*)d_in[3];
  const float* g21    = (const float*)d_in[4];
  const float* b21    = (const float*)d_in[5];
  const float* g12    = (const float*)d_in[6];
  const float* b12    = (const float*)d_in[7];
  const float* w_qkv1 = (const float*)d_in[8];
  const float* w_qkv2 = (const float*)d_in[9];
  const float* o1dw   = (const float*)d_in[10];
  const float* o1lg   = (const float*)d_in[11];
  const float* o1lb   = (const float*)d_in[12];
  const float* o1w    = (const float*)d_in[13];
  const float* o1bi   = (const float*)d_in[14];
  const float* o2dw   = (const float*)d_in[15];
  const float* o2lg   = (const float*)d_in[16];
  const float* o2lb   = (const float*)d_in[17];
  const float* o2w    = (const float*)d_in[18];
  const float* o2bi   = (const float*)d_in[19];
  const float* rpb    = (const float*)d_in[20];
  const float* proj_w = (const float*)d_in[21];
  const float* proj_b = (const float*)d_in[22];
  const float* fc1_w  = (const float*)d_in[23];
  const float* fc1_b  = (const float*)d_in[24];
  const float* dw_w   = (const float*)d_in[25];
  const float* dw_b   = (const float*)d_in[26];
  const float* fc2_w  = (const float*)d_in[27];
  const float* fc2_b  = (const float*)d_in[28];
  float* out = (float*)d_out;

  // ---- workspace layout (word offsets; aliased by live range) ----
  float* ws = (float*)d_ws;
  ushort* xcc   = (ushort*)(ws + 0);           // 9,437,184 bf16
  ushort* ycc   = (ushort*)(ws + 4718592);     // 9,437,184 bf16
  float*  q1p   = ws + 4718592;                // 2,359,296 f32 (after ycc dead)
  float*  tbuf  = ws + 7077888;                // 2,359,296 f32
  float*  qkv1cc= ws + 9437184;                // 7,077,888 f32
  float*  kv2cc = ws + 16515072;               // 4,718,592 f32
  float*  offb  = ws + 21233664;               // 2,654,208 f32
  float*  o_att = ws + 23887872;               // 2,359,296 f32
  ushort* hcc   = (ushort*)(ws + 0);           // 37,748,736 bf16 (stage 2)
  ushort* h2cc  = (ushort*)(ws + 18874368);    // 37,748,736 bf16
  float*  o1cc  = ws + 37748736;               // 9,437,184 f32
  float*  fc2cc = ws + 0;                      // 9,437,184 f32 (after hcc dead)
  const size_t SW = 47185920;
  float* m_x = ws + SW, *r_x = m_x + 36864, *m_y = r_x + 36864, *r_y = m_y + 36864;
  float* m_o = r_y + 36864, *r_o = m_o + 36864;
  ushort* Wg1bf = (ushort*)(ws + SW + 221184);      // 49,152 bf16
  float* sg1 = ws + SW + 245760, *wb1 = sg1 + 192;
  ushort* Wg2bf = (ushort*)(ws + SW + 246144);      // 32,768 bf16
  float* sg2 = ws + SW + 262528, *wb2 = sg2 + 128;
  ushort* Wgfbf = (ushort*)(ws + SW + 262784);      // 262,144 bf16
  float* sgf = ws + SW + 393856, *wbf = sgf + 1024;
  ushort* projbf = (ushort*)(ws + SW + 395904);     // 16,384 bf16
  ushort* fc2bf  = (ushort*)(ws + SW + 404096);     // 262,144 bf16

  // 1. weights -> bf16 (+LN fold); SCALE=0.125 folded into q rows of qkv1.
  //    1 wave per row, lane-strided K, shuffle-reduced row sums.
  k_prepbf<<<48, 256, 0, stream>>>(w_qkv1, g11, b11, Wg1bf, sg1, wb1, 192, 256, 64);
  k_prepbf<<<32, 256, 0, stream>>>(w_qkv2, g21, b21, Wg2bf, sg2, wb2, 128, 256, 0);
  k_prepbf<<<256, 256, 0, stream>>>(fc1_w, g12, b12, Wgfbf, sgf, wbf, 1024, 256, 0);
  k_prepbf<<<64, 256, 0, stream>>>(proj_w, nullptr, nullptr, projbf, nullptr, nullptr, 256, 64, 0);
  k_prepbf<<<64, 256, 0, stream>>>(fc2_w, nullptr, nullptr, fc2bf, nullptr, nullptr, 256, 1024, 0);

  // 2. LN stats + cc-bf16 activations
  k_ln_stats<<<144, 256, 0, stream>>>(x, m_x, r_x, 256);
  k_ln_stats<<<144, 256, 0, stream>>>(y, m_y, r_y, 256);
  k_tocc<<<dim3(144, 4, 4), 256, 0, stream>>>(x, xcc);
  k_tocc<<<dim3(144, 4, 4), 256, 0, stream>>>(y, ycc);

  // 3. qkv projections (MFMA, LN folded)
  k_gemmB<ushort, float, true, false><<<dim3(72, 3, 4), 256, 0, stream>>>(
      xcc, Wg1bf, m_x, r_x, sg1, wb1, nullptr, nullptr, qkv1cc, 256, 192);
  k_gemmB<ushort, float, true, false><<<dim3(72, 2, 4), 256, 0, stream>>>(
      ycc, Wg2bf, m_y, r_y, sg2, wb2, nullptr, nullptr, kv2cc, 256, 128);

  // 4. offset branches (q1 planar via x8-unscale transpose)
  k_q1p<<<dim3(144, 4), 256, 0, stream>>>(qkv1cc, q1p);
  k_dw3x3<<<dim3(36, 32, 8), 256, 0, stream>>>(q1p, o1dw, tbuf);
  k_ln_gelu32<<<288, 256, 0, stream>>>(tbuf, o1lg, o1lb);
  k_conv18<<<dim3(144, 18, 8), 64, 0, stream>>>(tbuf, o1w, o1bi, offb, 0);
  k_dw3x3<<<dim3(36, 32, 8), 256, 0, stream>>>(q1p, o2dw, tbuf);
  k_ln_gelu32<<<288, 256, 0, stream>>>(tbuf, o2lg, o2lb);
  k_conv18<<<dim3(144, 18, 8), 64, 0, stream>>>(tbuf, o2w, o2bi, offb, 1);

  // 5. fused deformable sampling + attention
  k_attn<<<9216, 256, 0, stream>>>(qkv1cc, kv2cc, offb, rpb, o_att);

  // 6. proj (MFMA) + residual(xcc)
  k_gemmB<float, float, false, true><<<dim3(72, 4, 4), 256, 0, stream>>>(
      o_att, projbf, nullptr, nullptr, nullptr, nullptr, proj_b, xcc, o1cc, 64, 256);

  // 7. MLP: LN stats, fc1 (MFMA, LN folded, bf16 out), dw+gelu cc, fc2 (MFMA)
  k_ln_stats_cc<<<9216, 256, 0, stream>>>(o1cc, m_o, r_o);
  k_gemmB<float, ushort, true, false><<<dim3(72, 16, 4), 256, 0, stream>>>(
      o1cc, Wgfbf, m_o, r_o, sgf, wbf, fc1_b, nullptr, hcc, 256, 1024);
  k_dwgelu_cc<<<dim3(36, 32, 4), 256, 0, stream>>>(hcc, dw_w, dw_b, h2cc);
  k_gemmB<ushort, float, false, false><<<dim3(72, 4, 4), 256, 0, stream>>>(
      h2cc, fc2bf, nullptr, nullptr, nullptr, nullptr, fc2_b, nullptr, fc2cc, 1024, 256);

  // 8. final transpose + residual(o1cc)
  k_fromcc<<<dim3(144, 4, 4), 256, 0, stream>>>(fc2cc, o1cc, out);
}

// Round 6
// 1073.604 us; speedup vs baseline: 1.9709x; 1.2890x over previous
//
#include <hip/hip_runtime.h>
#include <math.h>

// LDCA forward — bf16 MFMA GEMMs on channel-contiguous activations.
// B=4 C=256 H=W=96 HID=64 G=2 GC=32 KS=3 NK=9 MLP=1024

#define HH 96
#define WWD 96
#define HWP 9216
#define EPSV 1e-5f
#define RFV 9.0f

typedef unsigned short ushort;
typedef __attribute__((ext_vector_type(8))) short short8v;
typedef __attribute__((ext_vector_type(8))) ushort ushort8v;
typedef __attribute__((ext_vector_type(4))) float f32x4;

__device__ inline ushort f2bf(float f) {
  union { float f; unsigned u; } v; v.f = f;
  unsigned r = v.u + 0x7FFFu + ((v.u >> 16) & 1u);
  return (ushort)(r >> 16);
}
__device__ inline float bf2f(ushort h) {
  union { unsigned u; float f; } v; v.u = ((unsigned)h) << 16;
  return v.f;
}

__device__ inline void stf(float* p, float v) { *p = v; }
__device__ inline void stf(ushort* p, float v) { *p = f2bf(v); }

// stage 16 elements (f32->bf16 convert, or bf16 copy) into LDS
__device__ inline void stage16(const float* __restrict__ s, ushort* d) {
  const float4* s4 = (const float4*)s;
  float4 v0 = s4[0], v1 = s4[1], v2 = s4[2], v3 = s4[3];
  ushort8v r0, r1;
  r0[0] = f2bf(v0.x); r0[1] = f2bf(v0.y); r0[2] = f2bf(v0.z); r0[3] = f2bf(v0.w);
  r0[4] = f2bf(v1.x); r0[5] = f2bf(v1.y); r0[6] = f2bf(v1.z); r0[7] = f2bf(v1.w);
  r1[0] = f2bf(v2.x); r1[1] = f2bf(v2.y); r1[2] = f2bf(v2.z); r1[3] = f2bf(v2.w);
  r1[4] = f2bf(v3.x); r1[5] = f2bf(v3.y); r1[6] = f2bf(v3.z); r1[7] = f2bf(v3.w);
  ((ushort8v*)d)[0] = r0; ((ushort8v*)d)[1] = r1;
}
__device__ inline void stage16(const ushort* __restrict__ s, ushort* d) {
  ((ushort8v*)d)[0] = ((const ushort8v*)s)[0];
  ((ushort8v*)d)[1] = ((const ushort8v*)s)[1];
}

// ---------------- LN stats over Cn planar channels (per pixel) ----------------
__global__ __launch_bounds__(256) void k_ln_stats(const float* __restrict__ in,
                                                  float* __restrict__ mout,
                                                  float* __restrict__ rout, int Cn) {
  int idx = blockIdx.x * 256 + threadIdx.x;
  int b = idx / HWP, p = idx % HWP;
  const float* base = in + (size_t)b * Cn * HWP + p;
  float s = 0.f, ss = 0.f;
  for (int c = 0; c < Cn; ++c) { float v = base[(size_t)c * HWP]; s += v; ss += v * v; }
  float m = s / (float)Cn;
  float var = ss / (float)Cn - m * m;
  mout[idx] = m;
  rout[idx] = rsqrtf(var + EPSV);
}

// ---------------- LN stats, channel-contiguous input (256 ch) ----------------
__global__ __launch_bounds__(256) void k_ln_stats_cc(const float* __restrict__ in,
                                                     float* __restrict__ mout,
                                                     float* __restrict__ rout) {
  int px = blockIdx.x * 4 + (threadIdx.x >> 6);
  int lane = threadIdx.x & 63;
  float4 v = *(const float4*)(in + (size_t)px * 256 + lane * 4);
  float s = v.x + v.y + v.z + v.w;
  float ss = v.x * v.x + v.y * v.y + v.z * v.z + v.w * v.w;
#pragma unroll
  for (int d = 1; d < 64; d <<= 1) { s += __shfl_xor(s, d); ss += __shfl_xor(ss, d); }
  if (lane == 0) {
    float m = s / 256.f;
    mout[px] = m;
    rout[px] = rsqrtf(ss / 256.f - m * m + EPSV);
  }
}

// ---------------- prep: bf16 weights + LN-fold vectors (1 wave / row) ----------------
__global__ __launch_bounds__(256) void k_prepbf(const float* __restrict__ w,
                                                const float* __restrict__ g,
                                                const float* __restrict__ beta,
                                                ushort* __restrict__ wbf,
                                                float* __restrict__ sg, float* __restrict__ wb,
                                                int O, int K, int scaleRows) {
  int o = blockIdx.x * 4 + (threadIdx.x >> 6);
  int lane = threadIdx.x & 63;
  if (o >= O) return;
  float sc = (o < scaleRows) ? 0.125f : 1.f;
  float sgv = 0.f, wbv = 0.f;
  for (int c = lane; c < K; c += 64) {
    float wv = w[(size_t)o * K + c];
    float t = wv * (g ? g[c] : 1.f) * sc;
    ushort u = f2bf(t);
    wbf[(size_t)o * K + c] = u;
    sgv += bf2f(u);
    wbv += wv * (beta ? beta[c] : 0.f);
  }
#pragma unroll
  for (int d = 1; d < 64; d <<= 1) { sgv += __shfl_xor(sgv, d); wbv += __shfl_xor(wbv, d); }
  if (lane == 0) {
    if (sg) sg[o] = sgv;
    if (wb) wb[o] = wbv * sc;
  }
}

// ---------------- planar f32 -> channel-contiguous bf16 ----------------
__global__ __launch_bounds__(256) void k_tocc(const float* __restrict__ src,
                                              ushort* __restrict__ dst) {
  __shared__ float tile[64][65];
  int tp = threadIdx.x & 63, tq = threadIdx.x >> 6;
  int p0 = blockIdx.x * 64, c0 = blockIdx.y * 64, b = blockIdx.z;
#pragma unroll 4
  for (int i = 0; i < 16; ++i) {
    int ch = tq * 16 + i;
    tile[ch][tp] = src[((size_t)b * 256 + c0 + ch) * HWP + p0 + tp];
  }
  __syncthreads();
#pragma unroll 4
  for (int i = 0; i < 16; ++i) {
    int pp = tq * 16 + i;
    dst[((size_t)b * HWP + p0 + pp) * 256 + c0 + tp] = f2bf(tile[tp][pp]);
  }
}

// ---------------- MFMA GEMM (orientation B): out_cc[b][p][o] ----------------
template <typename TI, typename TO, bool LNF, bool RES>
__global__ __launch_bounds__(256) void k_gemmB(const TI* __restrict__ act,
                                               const ushort* __restrict__ Wbf,
                                               const float* __restrict__ ms,
                                               const float* __restrict__ rs,
                                               const float* __restrict__ sg,
                                               const float* __restrict__ wb,
                                               const float* __restrict__ bias,
                                               const ushort* __restrict__ resid,
                                               TO* __restrict__ outp, int K, int O) {
  __shared__ ushort at[128][56];  // padded: 112 B row stride (16B-aligned)
  __shared__ ushort wt[64][56];
  int tid = threadIdx.x;
  int lane = tid & 63, wv = tid >> 6;
  int wr = wv >> 1, wc = wv & 1;
  int p0 = blockIdx.x * 128, o0 = blockIdx.y * 64, b = blockIdx.z;
  size_t pb = (size_t)b * HWP;
  int l15 = lane & 15, lk = (lane >> 4) * 8;
  f32x4 acc[4][2];
#pragma unroll
  for (int rt = 0; rt < 4; ++rt)
#pragma unroll
    for (int ct = 0; ct < 2; ++ct) { acc[rt][ct][0] = 0.f; acc[rt][ct][1] = 0.f; acc[rt][ct][2] = 0.f; acc[rt][ct][3] = 0.f; }

  for (int kb = 0; kb < K; kb += 32) {
    __syncthreads();
    {
      int p = tid >> 1, kh = (tid & 1) * 16;
      stage16(act + (pb + p0 + p) * (size_t)K + kb + kh, &at[p][kh]);
    }
    if (tid < 128) {
      int o = tid >> 1, kh = (tid & 1) * 16;
      stage16(Wbf + (size_t)(o0 + o) * K + kb + kh, &wt[o][kh]);
    }
    __syncthreads();
    short8v a[4], bb[2];
#pragma unroll
    for (int rt = 0; rt < 4; ++rt) a[rt] = *(const short8v*)&at[wr * 64 + rt * 16 + l15][lk];
#pragma unroll
    for (int ct = 0; ct < 2; ++ct) bb[ct] = *(const short8v*)&wt[wc * 32 + ct * 16 + l15][lk];
#pragma unroll
    for (int rt = 0; rt < 4; ++rt)
#pragma unroll
      for (int ct = 0; ct < 2; ++ct)
        acc[rt][ct] = __builtin_amdgcn_mfma_f32_16x16x32_bf16(a[rt], bb[ct], acc[rt][ct], 0, 0, 0);
  }
  // epilogue: D col(lane&15)=o, row((lane>>4)*4+j)=p  [m89-verified mapping]
#pragma unroll
  for (int rt = 0; rt < 4; ++rt) {
    int pbase = p0 + wr * 64 + rt * 16 + (lane >> 4) * 4;
#pragma unroll
    for (int j = 0; j < 4; ++j) {
      int p = pbase + j;
      float rr = 0.f, mm = 0.f;
      if (LNF) { rr = rs[b * HWP + p]; mm = ms[b * HWP + p]; }
#pragma unroll
      for (int ct = 0; ct < 2; ++ct) {
        int o = o0 + wc * 32 + ct * 16 + l15;
        float v = acc[rt][ct][j];
        if (LNF) v = rr * v - rr * mm * sg[o];
        if (wb) v += wb[o];
        if (bias) v += bias[o];
        if (RES) v += bf2f(resid[(pb + p) * (size_t)O + o]);
        stf(&outp[(pb + p) * (size_t)O + o], v);
      }
    }
  }
}

// ---------------- q1 slice of qkv1cc -> planar f32 (x8 to unscale) ----------------
__global__ __launch_bounds__(256) void k_q1p(const float* __restrict__ qkv1cc,
                                             float* __restrict__ q1p) {
  __shared__ float tile[64][65];
  int tp = threadIdx.x & 63, tq = threadIdx.x >> 6;
  int p0 = blockIdx.x * 64, b = blockIdx.y;
#pragma unroll 4
  for (int i = 0; i < 16; ++i) {
    int pp = tq * 16 + i;
    tile[tp][pp] = qkv1cc[((size_t)b * HWP + p0 + pp) * 192 + tp];
  }
  __syncthreads();
#pragma unroll 4
  for (int i = 0; i < 16; ++i) {
    int ch = tq * 16 + i;
    q1p[((size_t)b * 64 + ch) * HWP + p0 + tp] = tile[ch][tp] * 8.f;
  }
}

// ---------------- offset branches: depthwise 3x3 on q1 (both branches, z=16) --------
__global__ __launch_bounds__(256) void k_dw3x3(const float* __restrict__ q1p,
                                               const float* __restrict__ dww1,
                                               const float* __restrict__ dww2,
                                               float* __restrict__ t) {
  int p = blockIdx.x * 256 + threadIdx.x;
  int c = blockIdx.y, z = blockIdx.z;   // z = s*8 + bg
  int bg = z & 7;
  int b = bg >> 1, g = bg & 1;
  const float* dww = (z >= 8) ? dww2 : dww1;
  int y = p / WWD, x = p % WWD;
  const float* src = q1p + ((size_t)b * 64 + g * 32 + c) * HWP;
  float acc = 0.f;
#pragma unroll
  for (int ky = 0; ky < 3; ++ky) {
    int yy = y + ky - 1;
    if (yy < 0 || yy >= HH) continue;
#pragma unroll
    for (int kx = 0; kx < 3; ++kx) {
      int xx = x + kx - 1;
      if (xx < 0 || xx >= WWD) continue;
      acc += src[yy * WWD + xx] * dww[c * 9 + ky * 3 + kx];
    }
  }
  t[(size_t)(z * 32 + c) * HWP + p] = acc;
}

// ---------------- offset branches: LN(32ch) + exact GELU, in place, z=16 ------------
__global__ __launch_bounds__(256) void k_ln_gelu32(float* __restrict__ t,
                                                   const float* __restrict__ g1,
                                                   const float* __restrict__ b1,
                                                   const float* __restrict__ g2,
                                                   const float* __restrict__ b2) {
  int idx = blockIdx.x * 256 + threadIdx.x;  // over 16*HW
  int z = idx / HWP, p = idx % HWP;
  const float* g = (z >= 8) ? g2 : g1;
  const float* bb = (z >= 8) ? b2 : b1;
  float* base = t + (size_t)z * 32 * HWP + p;
  float s = 0.f, ss = 0.f;
#pragma unroll
  for (int c = 0; c < 32; ++c) { float v = base[(size_t)c * HWP]; s += v; ss += v * v; }
  float m = s / 32.f;
  float var = ss / 32.f - m * m;
  float r = rsqrtf(var + EPSV);
#pragma unroll
  for (int c = 0; c < 32; ++c) {
    float v = base[(size_t)c * HWP];
    float xn = (v - m) * r * g[c] + bb[c];
    base[(size_t)c * HWP] = 0.5f * xn * (1.f + erff(xn * 0.70710678118654752f));
  }
}

// ---------------- offset branches: 3x3 conv 32->18, tanh*RF + base ----------------
// Tile kernel: 16x16 px, 18x18x32 halo in LDS shared across all 18 oc.
// Weights read wave-uniformly from global (scalar pipe).
__global__ __launch_bounds__(256) void k_conv18(const float* __restrict__ t,
                                                const float* __restrict__ w1,
                                                const float* __restrict__ b1,
                                                const float* __restrict__ w2,
                                                const float* __restrict__ b2,
                                                float* __restrict__ offo) {
  __shared__ float in_t[32 * 324];  // 41.5 KB
  int tid = threadIdx.x;
  int tile = blockIdx.x, z = blockIdx.y;  // z = s*8 + bg
  int ty0 = (tile / 6) * 16, tx0 = (tile % 6) * 16;
  const float* w = (z >= 8) ? w2 : w1;
  const float* bias = (z >= 8) ? b2 : b1;
  const float* tb = t + (size_t)z * 32 * HWP;
  for (int idx = tid; idx < 32 * 324; idx += 256) {
    int c = idx / 324, pp = idx % 324;
    int gy = ty0 - 1 + pp / 18, gx = tx0 - 1 + pp % 18;
    float v = 0.f;
    if (gy >= 0 && gy < HH && gx >= 0 && gx < WWD) v = tb[(size_t)c * HWP + gy * WWD + gx];
    in_t[idx] = v;
  }
  __syncthreads();
  int ly = tid >> 4, lx = tid & 15;
  float acc[18];
#pragma unroll
  for (int oc = 0; oc < 18; ++oc) acc[oc] = bias[oc];
  const float* basep = in_t + ly * 18 + lx;
  for (int c = 0; c < 32; ++c) {
#pragma unroll
    for (int dy = 0; dy < 3; ++dy)
#pragma unroll
      for (int dx = 0; dx < 3; ++dx) {
        float v = basep[c * 324 + dy * 18 + dx];
        int tap = c * 9 + dy * 3 + dx;
#pragma unroll
        for (int oc = 0; oc < 18; ++oc)
          acc[oc] = fmaf(v, w[oc * 288 + tap], acc[oc]);
      }
  }
  int p = (ty0 + ly) * WWD + tx0 + lx;
#pragma unroll
  for (int oc = 0; oc < 18; ++oc) {
    int n = oc >> 1, d = oc & 1;
    float basev = d ? (float)(n % 3 - 1) : (float)(n / 3 - 1);
    offo[((size_t)z * 18 + oc) * HWP + p] = tanhf(acc[oc]) * RFV + basev;
  }
}

// ---------------- fused deformable sampling + softmax + PV ----------------
__global__ __launch_bounds__(256) void k_attn(const float* __restrict__ qkv1cc,
                                              const float* __restrict__ kv2cc,
                                              const float* __restrict__ offo,
                                              const float* __restrict__ rpb,
                                              float* __restrict__ o_att) {
  __shared__ float rl[576];
  for (int i = threadIdx.x; i < 576; i += 256) rl[i] = rpb[i];
  __syncthreads();
  int pix = blockIdx.x * 4 + (threadIdx.x >> 6);
  int l = threadIdx.x & 63;
  int b = pix / HWP, p = pix % HWP;
  int y = p / WWD, x = p % WWD;
  int g = l >> 5;
  int bg = b * 2 + g;
  float qv = qkv1cc[((size_t)b * HWP + p) * 192 + l];
  float scores[18], vvv[18];
#pragma unroll
  for (int s = 0; s < 2; ++s) {
    const float* offp = offo + ((size_t)(s * 8 + bg) * 18) * HWP + p;
    const float* kvb = s ? (kv2cc + (size_t)b * HWP * 128) : (qkv1cc + (size_t)b * HWP * 192);
    int stride = s ? 128 : 192;
    int koff = s ? 0 : 64;
#pragma unroll
    for (int n = 0; n < 9; ++n) {
      float ry = (float)y + offp[(size_t)(2 * n) * HWP];
      float rx = (float)x + offp[(size_t)(2 * n + 1) * HWP];
      float y0f = floorf(ry), x0f = floorf(rx);
      float wy = ry - y0f, wx = rx - x0f;
      int y0 = (int)y0f, x0 = (int)x0f;
      float ka = 0.f, va = 0.f;
#pragma unroll
      for (int cy = 0; cy < 2; ++cy) {
        int yi = y0 + cy;
        if (yi < 0 || yi >= HH) continue;
        float wyc = cy ? wy : 1.f - wy;
#pragma unroll
        for (int cx = 0; cx < 2; ++cx) {
          int xi = x0 + cx;
          if (xi < 0 || xi >= WWD) continue;
          float wgt = wyc * (cx ? wx : 1.f - wx);
          const float* row = kvb + (size_t)(yi * WWD + xi) * stride + koff;
          ka += wgt * row[l];
          va += wgt * row[64 + l];
        }
      }
      float sp = qv * (ka + rl[n * 64 + l]);
      sp += __shfl_xor(sp, 1);
      sp += __shfl_xor(sp, 2);
      sp += __shfl_xor(sp, 4);
      sp += __shfl_xor(sp, 8);
      sp += __shfl_xor(sp, 16);
      sp += __shfl_xor(sp, 32);
      scores[s * 9 + n] = sp;
      vvv[s * 9 + n] = va;
    }
  }
  float mx = scores[0];
#pragma unroll
  for (int i = 1; i < 18; ++i) mx = fmaxf(mx, scores[i]);
  float sum = 0.f;
#pragma unroll
  for (int i = 0; i < 18; ++i) { scores[i] = expf(scores[i] - mx); sum += scores[i]; }
  float inv = 1.f / sum;
  float o = 0.f;
#pragma unroll
  for (int i = 0; i < 18; ++i) o += scores[i] * vvv[i];
  o_att[((size_t)b * HWP + p) * 64 + l] = o * inv;
}

// ---------------- depthwise 3x3 + gelu(h+hd), channel-contiguous bf16 ----------------
__global__ __launch_bounds__(256) void k_dwgelu_cc(const ushort* __restrict__ h,
                                                   const float* __restrict__ w,
                                                   const float* __restrict__ bias,
                                                   ushort* __restrict__ h2) {
  __shared__ ushort tileh[324][48];  // 18x18 px halo tile x 32 ch (96 B rows, aligned)
  __shared__ float wl[32][9];
  __shared__ float bl[32];
  int tid = threadIdx.x;
  int tile = blockIdx.x, chb = blockIdx.y, b = blockIdx.z;
  int ty0 = (tile / 6) * 16, tx0 = (tile % 6) * 16;
  size_t base = ((size_t)b * HWP) * 1024 + chb * 32;
  for (int i = tid; i < 288; i += 256) wl[i / 9][i % 9] = w[(chb * 32 + i / 9) * 9 + i % 9];
  if (tid < 32) bl[tid] = bias[chb * 32 + tid];
  for (int idx = tid; idx < 324; idx += 256) {
    int py = idx / 18, px = idx % 18;
    int gy = ty0 - 1 + py, gx = tx0 - 1 + px;
    ushort8v* d = (ushort8v*)&tileh[idx][0];
    if (gy >= 0 && gy < HH && gx >= 0 && gx < WWD) {
      const ushort8v* sv = (const ushort8v*)(h + base + (size_t)(gy * WWD + gx) * 1024);
      d[0] = sv[0]; d[1] = sv[1]; d[2] = sv[2]; d[3] = sv[3];
    } else {
      ushort8v z;
#pragma unroll
      for (int e = 0; e < 8; ++e) z[e] = 0;
      d[0] = z; d[1] = z; d[2] = z; d[3] = z;
    }
  }
  __syncthreads();
  int ly = tid >> 4, lx = tid & 15;
  float a[32];
#pragma unroll
  for (int c = 0; c < 32; ++c) a[c] = bl[c];
#pragma unroll
  for (int dy = 0; dy < 3; ++dy)
#pragma unroll
    for (int dx = 0; dx < 3; ++dx) {
      const ushort8v* t = (const ushort8v*)&tileh[(ly + dy) * 18 + lx + dx][0];
      int tap = dy * 3 + dx;
#pragma unroll
      for (int cq = 0; cq < 4; ++cq) {
        ushort8v vv = t[cq];
#pragma unroll
        for (int e = 0; e < 8; ++e) a[cq * 8 + e] += bf2f(vv[e]) * wl[cq * 8 + e][tap];
      }
    }
  const ushort8v* ctr = (const ushort8v*)&tileh[(ly + 1) * 18 + lx + 1][0];
  ushort8v* outv = (ushort8v*)(h2 + base + (size_t)((ty0 + ly) * WWD + tx0 + lx) * 1024);
#pragma unroll
  for (int cq = 0; cq < 4; ++cq) {
    ushort8v vv = ctr[cq];
    ushort8v rv;
#pragma unroll
    for (int e = 0; e < 8; ++e) {
      float v = bf2f(vv[e]) + a[cq * 8 + e];
      rv[e] = f2bf(0.5f * v * (1.f + erff(v * 0.70710678118654752f)));
    }
    outv[cq] = rv;
  }
}

// ---------------- final: out_planar = fc2cc + o1cc (transpose-add) ----------------
__global__ __launch_bounds__(256) void k_fromcc(const float* __restrict__ fc2cc,
                                                const float* __restrict__ o1cc,
                                                float* __restrict__ outp) {
  __shared__ float tile[64][65];
  int tp = threadIdx.x & 63, tq = threadIdx.x >> 6;
  int p0 = blockIdx.x * 64, c0 = blockIdx.y * 64, b = blockIdx.z;
#pragma unroll 4
  for (int i = 0; i < 16; ++i) {
    int pp = tq * 16 + i;
    size_t idx = ((size_t)b * HWP + p0 + pp) * 256 + c0 + tp;
    tile[tp][pp] = fc2cc[idx] + o1cc[idx];
  }
  __syncthreads();
#pragma unroll 4
  for (int i = 0; i < 16; ++i) {
    int ch = tq * 16 + i;
    outp[((size_t)b * 256 + c0 + ch) * HWP + p0 + tp] = tile[ch][tp];
  }
}

extern "C" void kernel_launch(void* const* d_in, const int* in_sizes, int n_in,
                              void* d_out, int out_size, void* d_ws, size_t ws_size,
                              hipStream_t stream) {
  const float* x      = (const float*)d_in[0];
  const float* y      = (const float*)d_in[1];
  const float* g11    = (const float*)d_in[2];
  const float* b11    = (const float*)d_in[3];
  const float* g21    = (const float*)d_in[4];
  const float* b21    = (const float*)d_in[5];
  const float* g12    = (const float*)d_in[6];
  const float* b12    = (const float*)d_in[7];
  const float* w_qkv1 = (const float*)d_in[8];
  const float* w_qkv2 = (const float*)d_in[9];
  const float* o1dw   = (const float*)d_in[10];
  const float* o1lg   = (const float*)d_in[11];
  const float* o1lb   = (const float*)d_in[12];
  const float* o1w    = (const float*)d_in[13];
  const float* o1bi   = (const float*)d_in[14];
  const float* o2dw   = (const float*)d_in[15];
  const float* o2lg   = (const float*)d_in[16];
  const float* o2lb   = (const float*)d_in[17];
  const float* o2w    = (const float*)d_in[18];
  const float* o2bi   = (const float*)d_in[19];
  const float* rpb    = (const float*)d_in[20];
  const float* proj_w = (const float*)d_in[21];
  const float* proj_b = (const float*)d_in[22];
  const float* fc1_w  = (const float*)d_in[23];
  const float* fc1_b  = (const float*)d_in[24];
  const float* dw_w   = (const float*)d_in[25];
  const float* dw_b   = (const float*)d_in[26];
  const float* fc2_w  = (const float*)d_in[27];
  const float* fc2_b  = (const float*)d_in[28];
  float* out = (float*)d_out;

  // ---- workspace layout (word offsets; aliased by live range) ----
  float* ws = (float*)d_ws;
  ushort* xcc   = (ushort*)(ws + 0);           // 9,437,184 bf16
  ushort* ycc   = (ushort*)(ws + 4718592);     // 9,437,184 bf16
  float*  q1p   = ws + 4718592;                // 2,359,296 f32 (after ycc dead)
  float*  qkv1cc= ws + 9437184;                // 7,077,888 f32
  float*  kv2cc = ws + 16515072;               // 4,718,592 f32
  float*  offb  = ws + 21233664;               // 2,654,208 f32
  float*  o_att = ws + 23887872;               // 2,359,296 f32
  float*  tbuf12= ws + 26247168;               // 4,718,592 f32 (both offset branches)
  ushort* hcc   = (ushort*)(ws + 0);           // 37,748,736 bf16 (stage 2)
  ushort* h2cc  = (ushort*)(ws + 18874368);    // 37,748,736 bf16
  float*  o1cc  = ws + 37748736;               // 9,437,184 f32
  float*  fc2cc = ws + 0;                      // 9,437,184 f32 (after hcc dead)
  const size_t SW = 47185920;
  float* m_x = ws + SW, *r_x = m_x + 36864, *m_y = r_x + 36864, *r_y = m_y + 36864;
  float* m_o = r_y + 36864, *r_o = m_o + 36864;
  ushort* Wg1bf = (ushort*)(ws + SW + 221184);      // 49,152 bf16
  float* sg1 = ws + SW + 245760, *wb1 = sg1 + 192;
  ushort* Wg2bf = (ushort*)(ws + SW + 246144);      // 32,768 bf16
  float* sg2 = ws + SW + 262528, *wb2 = sg2 + 128;
  ushort* Wgfbf = (ushort*)(ws + SW + 262784);      // 262,144 bf16
  float* sgf = ws + SW + 393856, *wbf = sgf + 1024;
  ushort* projbf = (ushort*)(ws + SW + 395904);     // 16,384 bf16
  ushort* fc2bf  = (ushort*)(ws + SW + 404096);     // 262,144 bf16

  // 1. weights -> bf16 (+LN fold); SCALE=0.125 folded into q rows of qkv1.
  k_prepbf<<<48, 256, 0, stream>>>(w_qkv1, g11, b11, Wg1bf, sg1, wb1, 192, 256, 64);
  k_prepbf<<<32, 256, 0, stream>>>(w_qkv2, g21, b21, Wg2bf, sg2, wb2, 128, 256, 0);
  k_prepbf<<<256, 256, 0, stream>>>(fc1_w, g12, b12, Wgfbf, sgf, wbf, 1024, 256, 0);
  k_prepbf<<<64, 256, 0, stream>>>(proj_w, nullptr, nullptr, projbf, nullptr, nullptr, 256, 64, 0);
  k_prepbf<<<64, 256, 0, stream>>>(fc2_w, nullptr, nullptr, fc2bf, nullptr, nullptr, 256, 1024, 0);

  // 2. LN stats + cc-bf16 activations
  k_ln_stats<<<144, 256, 0, stream>>>(x, m_x, r_x, 256);
  k_ln_stats<<<144, 256, 0, stream>>>(y, m_y, r_y, 256);
  k_tocc<<<dim3(144, 4, 4), 256, 0, stream>>>(x, xcc);
  k_tocc<<<dim3(144, 4, 4), 256, 0, stream>>>(y, ycc);

  // 3. qkv projections (MFMA, LN folded)
  k_gemmB<ushort, float, true, false><<<dim3(72, 3, 4), 256, 0, stream>>>(
      xcc, Wg1bf, m_x, r_x, sg1, wb1, nullptr, nullptr, qkv1cc, 256, 192);
  k_gemmB<ushort, float, true, false><<<dim3(72, 2, 4), 256, 0, stream>>>(
      ycc, Wg2bf, m_y, r_y, sg2, wb2, nullptr, nullptr, kv2cc, 256, 128);

  // 4. offset branches (both fused per kernel; z = s*8+bg)
  k_q1p<<<dim3(144, 4), 256, 0, stream>>>(qkv1cc, q1p);
  k_dw3x3<<<dim3(36, 32, 16), 256, 0, stream>>>(q1p, o1dw, o2dw, tbuf12);
  k_ln_gelu32<<<576, 256, 0, stream>>>(tbuf12, o1lg, o1lb, o2lg, o2lb);
  k_conv18<<<dim3(36, 16), 256, 0, stream>>>(tbuf12, o1w, o1bi, o2w, o2bi, offb);

  // 5. fused deformable sampling + attention
  k_attn<<<9216, 256, 0, stream>>>(qkv1cc, kv2cc, offb, rpb, o_att);

  // 6. proj (MFMA) + residual(xcc)
  k_gemmB<float, float, false, true><<<dim3(72, 4, 4), 256, 0, stream>>>(
      o_att, projbf, nullptr, nullptr, nullptr, nullptr, proj_b, xcc, o1cc, 64, 256);

  // 7. MLP: LN stats, fc1 (MFMA, LN folded, bf16 out), dw+gelu cc, fc2 (MFMA)
  k_ln_stats_cc<<<9216, 256, 0, stream>>>(o1cc, m_o, r_o);
  k_gemmB<float, ushort, true, false><<<dim3(72, 16, 4), 256, 0, stream>>>(
      o1cc, Wgfbf, m_o, r_o, sgf, wbf, fc1_b, nullptr, hcc, 256, 1024);
  k_dwgelu_cc<<<dim3(36, 32, 4), 256, 0, stream>>>(hcc, dw_w, dw_b, h2cc);
  k_gemmB<ushort, float, false, false><<<dim3(72, 4, 4), 256, 0, stream>>>(
      h2cc, fc2bf, nullptr, nullptr, nullptr, nullptr, fc2_b, nullptr, fc2cc, 1024, 256);

  // 8. final transpose + residual(o1cc)
  k_fromcc<<<dim3(144, 4, 4), 256, 0, stream>>>(fc2cc, o1cc, out);
}